// Round 1
// baseline (639.345 us; speedup 1.0000x reference)
//
#include <hip/hip_runtime.h>
#include <cstdint>
#include <cstddef>

// Sizes
#define LSEQ 4096
#define DI   512
#define NSTATE 16
#define NSEQ 8
#define TC 64     // scan chunk length
#define NCH 64    // number of chunks (LSEQ/TC)

// Workspace layout (floats):
//  xz   : [8][4096][1024]  = 33,554,432
//  xs   : [8][4096][512]   = 16,777,216  (becomes y in-place after scan pass3)
//  dbl  : [8][4096][48]    =  1,572,864
//  ap   : [8][64][512][16] =  4,194,304  (aprod; later aliased by ycomb [2][4096][512])
//  ps   : [8][64][512][16] =  4,194,304  (pstate; becomes hinit in-place after pass2)
// total = 60,293,120 floats = 241,172,480 bytes
#define XZ_OFF  0
#define XS_OFF  33554432
#define DBL_OFF 50331648
#define AP_OFF  51904512
#define PS_OFF  56098816

__device__ __forceinline__ float silu_f(float v) { return v / (1.f + __expf(-v)); }
__device__ __forceinline__ float softplus_f(float v) {
  return fmaxf(v, 0.f) + log1pf(__expf(-fabsf(v)));
}

// ---------------------------------------------------------------------------
// Kernel 1: xz[seq][t][0:1024] = z[seq][t][:] @ W_in   (z built on the fly
// from x with flips; each block covers one h-line (64 t) x 256 j cols)
// ---------------------------------------------------------------------------
__global__ __launch_bounds__(256) void k_gemm_in(const float* __restrict__ x,
                                                 const float* __restrict__ Win,
                                                 float* __restrict__ xz) {
  __shared__ float Ash[32][64];    // [k][t_local]
  __shared__ float Bsh[32][256];   // [k][j_local]
  const int bx  = blockIdx.x;          // 0..511 : seq*64 + h-line
  const int seq = bx >> 6, hl = bx & 63;
  const int j0  = blockIdx.y << 8;     // 4 tiles of 256 cols
  const int b   = seq & 1, dir = seq >> 1;
  const int hp  = (dir & 2) ? 63 - hl : hl;
  const int tid = threadIdx.x;
  const int wa = tid & 63, cgrp = tid >> 6;   // A-load lane mapping
  const int wp = (dir & 1) ? 63 - wa : wa;
  const float* xb = x + (size_t)b * (256 * 4096) + hp * 64 + wp;
  const int tx = tid & 31, ty = tid >> 5;

  float acc[8][8];
#pragma unroll
  for (int i = 0; i < 8; ++i)
#pragma unroll
    for (int j = 0; j < 8; ++j) acc[i][j] = 0.f;

  for (int kc = 0; kc < 256; kc += 32) {
#pragma unroll
    for (int i = 0; i < 8; ++i) {
      const int kk = cgrp + (i << 2);
      Ash[kk][wa] = xb[(size_t)(kc + kk) * 4096];
    }
#pragma unroll
    for (int i = 0; i < 8; ++i) {
      const int kk = cgrp + (i << 2);
      *(float4*)&Bsh[kk][wa << 2] =
          *(const float4*)&Win[(size_t)(kc + kk) * 1024 + j0 + (wa << 2)];
    }
    __syncthreads();
#pragma unroll
    for (int kk = 0; kk < 32; ++kk) {
      const float4 a0 = *(const float4*)&Ash[kk][ty * 8];
      const float4 a1 = *(const float4*)&Ash[kk][ty * 8 + 4];
      const float4 b0 = *(const float4*)&Bsh[kk][tx * 4];
      const float4 b1 = *(const float4*)&Bsh[kk][tx * 4 + 128];
      const float ar[8] = {a0.x, a0.y, a0.z, a0.w, a1.x, a1.y, a1.z, a1.w};
      const float br[8] = {b0.x, b0.y, b0.z, b0.w, b1.x, b1.y, b1.z, b1.w};
#pragma unroll
      for (int i = 0; i < 8; ++i)
#pragma unroll
        for (int j = 0; j < 8; ++j) acc[i][j] = fmaf(ar[i], br[j], acc[i][j]);
    }
    __syncthreads();
  }
  const int t0 = hl << 6;
  float* orow = xz + ((size_t)seq * LSEQ + t0 + ty * 8) * 1024 + j0;
#pragma unroll
  for (int i = 0; i < 8; ++i) {
    const float4 v0 = {acc[i][0], acc[i][1], acc[i][2], acc[i][3]};
    const float4 v1 = {acc[i][4], acc[i][5], acc[i][6], acc[i][7]};
    *(float4*)&orow[(size_t)i * 1024 + tx * 4] = v0;
    *(float4*)&orow[(size_t)i * 1024 + tx * 4 + 128] = v1;
  }
}

// ---------------------------------------------------------------------------
// Kernel 2: depthwise causal conv(4) + bias + silu : xm (xz cols 0..511) -> xs
// ---------------------------------------------------------------------------
__global__ __launch_bounds__(256) void k_conv(const float* __restrict__ xz,
                                              const float* __restrict__ cw,
                                              const float* __restrict__ cb,
                                              float* __restrict__ xs) {
  const int t0  = blockIdx.x << 4;   // 16 timesteps per block
  const int seq = blockIdx.y;
  const int d   = (blockIdx.z << 8) + threadIdx.x;
  const float* xm = xz + (size_t)seq * LSEQ * 1024 + d;
  const float w0 = cw[d * 4], w1 = cw[d * 4 + 1], w2 = cw[d * 4 + 2], w3 = cw[d * 4 + 3];
  const float bias = cb[d];
  float r0 = (t0 >= 3) ? xm[(size_t)(t0 - 3) * 1024] : 0.f;
  float r1 = (t0 >= 2) ? xm[(size_t)(t0 - 2) * 1024] : 0.f;
  float r2 = (t0 >= 1) ? xm[(size_t)(t0 - 1) * 1024] : 0.f;
  float* orow = xs + ((size_t)seq * LSEQ + t0) * DI + d;
#pragma unroll
  for (int i = 0; i < 16; ++i) {
    const float r3 = xm[(size_t)(t0 + i) * 1024];
    const float v = fmaf(w0, r0, fmaf(w1, r1, fmaf(w2, r2, fmaf(w3, r3, bias))));
    orow[(size_t)i * DI] = silu_f(v);
    r0 = r1; r1 = r2; r2 = r3;
  }
}

// ---------------------------------------------------------------------------
// Kernel 3: dbl[row][0:48] = xs[row][:] @ W_x   (16 rows per block)
// ---------------------------------------------------------------------------
__global__ __launch_bounds__(256) void k_gemm_x(const float* __restrict__ xs,
                                                const float* __restrict__ Wx,
                                                float* __restrict__ dbl) {
  __shared__ float xsh[16][512];
  const int rb  = blockIdx.x;
  const int tid = threadIdx.x;
  const int r = tid >> 4, k4 = tid & 15;
  const float* src = xs + (size_t)rb * 16 * DI;
#pragma unroll
  for (int i = 0; i < 8; ++i) {
    const int k = (i << 6) + (k4 << 2);
    *(float4*)&xsh[r][k] = *(const float4*)&src[(size_t)r * DI + k];
  }
  __syncthreads();
  if (tid < 192) {
    const int col = tid % 48;
    const int rg  = tid / 48;
    float a0 = 0.f, a1 = 0.f, a2 = 0.f, a3 = 0.f;
    for (int k = 0; k < 512; k += 4) {
      float wv0 = Wx[(size_t)(k + 0) * 48 + col];
      float wv1 = Wx[(size_t)(k + 1) * 48 + col];
      float wv2 = Wx[(size_t)(k + 2) * 48 + col];
      float wv3 = Wx[(size_t)(k + 3) * 48 + col];
      const float4 x0 = *(const float4*)&xsh[rg * 4 + 0][k];
      const float4 x1 = *(const float4*)&xsh[rg * 4 + 1][k];
      const float4 x2 = *(const float4*)&xsh[rg * 4 + 2][k];
      const float4 x3 = *(const float4*)&xsh[rg * 4 + 3][k];
      a0 = fmaf(x0.x, wv0, fmaf(x0.y, wv1, fmaf(x0.z, wv2, fmaf(x0.w, wv3, a0))));
      a1 = fmaf(x1.x, wv0, fmaf(x1.y, wv1, fmaf(x1.z, wv2, fmaf(x1.w, wv3, a1))));
      a2 = fmaf(x2.x, wv0, fmaf(x2.y, wv1, fmaf(x2.z, wv2, fmaf(x2.w, wv3, a2))));
      a3 = fmaf(x3.x, wv0, fmaf(x3.y, wv1, fmaf(x3.z, wv2, fmaf(x3.w, wv3, a3))));
    }
    const size_t base = ((size_t)rb * 16 + rg * 4) * 48 + col;
    dbl[base] = a0; dbl[base + 48] = a1; dbl[base + 96] = a2; dbl[base + 144] = a3;
  }
}

// ---------------------------------------------------------------------------
// Kernel 4 (scan pass 1): per (seq,chunk,d): running prod of dA and partial
// state with zero init. dt recomputed from dbl (softplus(dbl16 . Wdt_col + b)).
// ---------------------------------------------------------------------------
__global__ __launch_bounds__(256) void k_scan1(const float* __restrict__ xs,
                                               const float* __restrict__ dbl,
                                               const float* __restrict__ Wdt,
                                               const float* __restrict__ bdt,
                                               const float* __restrict__ Alog,
                                               float* __restrict__ aprod,
                                               float* __restrict__ pstate) {
  __shared__ float dsh[TC * 48];
  const int ch = blockIdx.x, seq = blockIdx.y;
  const int tid = threadIdx.x;
  const int d = (blockIdx.z << 8) + tid;
  const int t0 = ch << 6;
  const float* dsrc = dbl + ((size_t)seq * LSEQ + t0) * 48;
#pragma unroll
  for (int i = 0; i < 12; ++i) dsh[tid + (i << 8)] = dsrc[tid + (i << 8)];
  float wdt[16], Aa[16], st[16], P[16];
#pragma unroll
  for (int k = 0; k < 16; ++k) wdt[k] = Wdt[(size_t)k * DI + d];
  const float bd = bdt[d];
#pragma unroll
  for (int s = 0; s < NSTATE; ++s) {
    Aa[s] = -__expf(Alog[d * NSTATE + s]);
    st[s] = 0.f; P[s] = 1.f;
  }
  const float* xsrc = xs + ((size_t)seq * LSEQ + t0) * DI + d;
  __syncthreads();
  for (int t = 0; t < TC; ++t) {
    const float* dr = &dsh[t * 48];
    float dtp = bd;
#pragma unroll
    for (int k = 0; k < 16; ++k) dtp = fmaf(dr[k], wdt[k], dtp);
    const float dtv = softplus_f(dtp);
    const float u = dtv * xsrc[(size_t)t * DI];
#pragma unroll
    for (int s = 0; s < NSTATE; ++s) {
      const float a = __expf(dtv * Aa[s]);
      st[s] = fmaf(a, st[s], u * dr[16 + s]);
      P[s] *= a;
    }
  }
  float* ap = aprod  + (((size_t)seq * NCH + ch) * DI + d) * NSTATE;
  float* pp = pstate + (((size_t)seq * NCH + ch) * DI + d) * NSTATE;
#pragma unroll
  for (int s = 0; s < NSTATE; s += 4) {
    *(float4*)&ap[s] = make_float4(P[s], P[s + 1], P[s + 2], P[s + 3]);
    *(float4*)&pp[s] = make_float4(st[s], st[s + 1], st[s + 2], st[s + 3]);
  }
}

// ---------------------------------------------------------------------------
// Kernel 5 (scan pass 2): cross-chunk scan; pstate becomes hinit in-place.
// ---------------------------------------------------------------------------
__global__ __launch_bounds__(256) void k_scan2(const float* __restrict__ aprod,
                                               float* __restrict__ pstate) {
  const int flat = blockIdx.x * 256 + threadIdx.x;   // 0..65535
  const int seq = flat >> 13;
  const int rem = flat & 8191;                        // d*16+s
  const size_t stride = (size_t)DI * NSTATE;          // per-chunk
  const size_t base = (size_t)seq * NCH * stride + rem;
  float h = 0.f;
  for (int ch = 0; ch < NCH; ++ch) {
    const size_t o = base + (size_t)ch * stride;
    const float a = aprod[o];
    const float bsum = pstate[o];
    pstate[o] = h;               // hinit for this chunk
    h = fmaf(a, h, bsum);
  }
}

// ---------------------------------------------------------------------------
// Kernel 6 (scan pass 3): replay with correct init, produce
// y = (scan_y + xs*D) * silu(gate), written over xs in place.
// ---------------------------------------------------------------------------
__global__ __launch_bounds__(256) void k_scan3(const float* __restrict__ xz,
                                               float* __restrict__ xs,
                                               const float* __restrict__ dbl,
                                               const float* __restrict__ Wdt,
                                               const float* __restrict__ bdt,
                                               const float* __restrict__ Alog,
                                               const float* __restrict__ Dv,
                                               const float* __restrict__ hinit) {
  __shared__ float dsh[TC * 48];
  const int ch = blockIdx.x, seq = blockIdx.y;
  const int tid = threadIdx.x;
  const int d = (blockIdx.z << 8) + tid;
  const int t0 = ch << 6;
  const float* dsrc = dbl + ((size_t)seq * LSEQ + t0) * 48;
#pragma unroll
  for (int i = 0; i < 12; ++i) dsh[tid + (i << 8)] = dsrc[tid + (i << 8)];
  float wdt[16], Aa[16], st[16];
#pragma unroll
  for (int k = 0; k < 16; ++k) wdt[k] = Wdt[(size_t)k * DI + d];
  const float bd = bdt[d];
  const float Dp = Dv[d];
  const float* hp = hinit + (((size_t)seq * NCH + ch) * DI + d) * NSTATE;
#pragma unroll
  for (int s = 0; s < NSTATE; ++s) {
    Aa[s] = -__expf(Alog[d * NSTATE + s]);
    st[s] = hp[s];
  }
  float* xrow = xs + ((size_t)seq * LSEQ + t0) * DI + d;
  const float* grow = xz + ((size_t)seq * LSEQ + t0) * 1024 + 512 + d;
  __syncthreads();
  for (int t = 0; t < TC; ++t) {
    const float* dr = &dsh[t * 48];
    float dtp = bd;
#pragma unroll
    for (int k = 0; k < 16; ++k) dtp = fmaf(dr[k], wdt[k], dtp);
    const float dtv = softplus_f(dtp);
    const float xsv = xrow[(size_t)t * DI];
    const float u = dtv * xsv;
    float y = 0.f;
#pragma unroll
    for (int s = 0; s < NSTATE; ++s) {
      const float a = __expf(dtv * Aa[s]);
      st[s] = fmaf(a, st[s], u * dr[16 + s]);
      y = fmaf(st[s], dr[32 + s], y);
    }
    y = fmaf(xsv, Dp, y);
    const float g = grow[(size_t)t * 1024];
    y *= silu_f(g);
    xrow[(size_t)t * DI] = y;
  }
}

// ---------------------------------------------------------------------------
// Kernel 7: combine 4 directions (unflip + sum, x0.25): yc[b][t][d]
// ---------------------------------------------------------------------------
__global__ __launch_bounds__(256) void k_combine(const float* __restrict__ y,
                                                 float* __restrict__ yc) {
  const int flat = blockIdx.x * 256 + threadIdx.x;  // 2*4096*512 total
  const int d = flat & 511;
  const int t = (flat >> 9) & 4095;
  const int b = flat >> 21;
  const int h = t >> 6, w = t & 63;
  const int t1 = (h << 6) | (63 - w);
  const int t2 = ((63 - h) << 6) | w;
  const int t3 = ((63 - h) << 6) | (63 - w);
  const float v = y[((size_t)(0 + b) * LSEQ + t)  * DI + d] +
                  y[((size_t)(2 + b) * LSEQ + t1) * DI + d] +
                  y[((size_t)(4 + b) * LSEQ + t2) * DI + d] +
                  y[((size_t)(6 + b) * LSEQ + t3) * DI + d];
  yc[flat] = 0.25f * v;
}

// ---------------------------------------------------------------------------
// Kernel 8: out[b][c][t] = yc[b][t][:] @ W_out[:][c]   (transposed store via LDS)
// ---------------------------------------------------------------------------
__global__ __launch_bounds__(256) void k_gemm_out(const float* __restrict__ yc,
                                                  const float* __restrict__ Wout,
                                                  float* __restrict__ out) {
  __shared__ float smem[64 * 64 + 64 * 128];  // Ash [row][k] (64x64), Bsh [k][c] (64x128)
  float* Ash = smem;              // row-major [t_local][k] stride 64
  float* Bsh = smem + 64 * 64;    // [k][c_local] stride 128
  const int bt = blockIdx.x;      // 0..127 : b*64 + t-tile
  const int b = bt >> 6, tt = bt & 63;
  const int t0 = tt << 6;
  const int c0 = blockIdx.y << 7;
  const int tid = threadIdx.x;
  const int rq = tid >> 4, k4 = tid & 15;
  const int cq = tid & 31, dr8 = tid >> 5;
  const int tx = tid & 31, ty = tid >> 5;
  float acc[8][4];
#pragma unroll
  for (int i = 0; i < 8; ++i)
#pragma unroll
    for (int j = 0; j < 4; ++j) acc[i][j] = 0.f;

  for (int kc = 0; kc < 512; kc += 64) {
#pragma unroll
    for (int i = 0; i < 4; ++i) {
      const int row = rq + (i << 4);
      const float4 v = *(const float4*)&yc[((size_t)b * LSEQ + t0 + row) * DI + kc + (k4 << 2)];
      *(float4*)&Ash[row * 64 + (k4 << 2)] = v;
    }
#pragma unroll
    for (int i = 0; i < 8; ++i) {
      const int kk = dr8 + (i << 3);
      *(float4*)&Bsh[kk * 128 + cq * 4] =
          *(const float4*)&Wout[(size_t)(kc + kk) * 256 + c0 + cq * 4];
    }
    __syncthreads();
#pragma unroll
    for (int kk = 0; kk < 64; ++kk) {
      const float4 bv = *(const float4*)&Bsh[kk * 128 + tx * 4];
      const float br[4] = {bv.x, bv.y, bv.z, bv.w};
#pragma unroll
      for (int i = 0; i < 8; ++i) {
        const float av = Ash[(ty * 8 + i) * 64 + kk];
#pragma unroll
        for (int j = 0; j < 4; ++j) acc[i][j] = fmaf(av, br[j], acc[i][j]);
      }
    }
    __syncthreads();
  }
  // stage transposed into LDS, then coalesced store (t contiguous per c)
  float* Clds = smem;  // [c_local][t_local] stride 65 (scalar access only)
  __syncthreads();
#pragma unroll
  for (int i = 0; i < 8; ++i)
#pragma unroll
    for (int j = 0; j < 4; ++j) Clds[(tx * 4 + j) * 65 + ty * 8 + i] = acc[i][j];
  __syncthreads();
#pragma unroll
  for (int rr = 0; rr < 32; ++rr) {
    const int idx = rr * 256 + tid;
    const int cl = idx >> 6, tl = idx & 63;
    out[((size_t)b * 256 + c0 + cl) * LSEQ + t0 + tl] = Clds[cl * 65 + tl];
  }
}

// ---------------------------------------------------------------------------
extern "C" void kernel_launch(void* const* d_in, const int* in_sizes, int n_in,
                              void* d_out, int out_size, void* d_ws, size_t ws_size,
                              hipStream_t stream) {
  const float* x     = (const float*)d_in[0];
  const float* W_in  = (const float*)d_in[1];
  const float* convw = (const float*)d_in[2];
  const float* convb = (const float*)d_in[3];
  const float* W_x   = (const float*)d_in[4];
  const float* W_dt  = (const float*)d_in[5];
  const float* b_dt  = (const float*)d_in[6];
  const float* A_log = (const float*)d_in[7];
  const float* Dvec  = (const float*)d_in[8];
  const float* W_out = (const float*)d_in[9];
  float* out = (float*)d_out;

  float* ws  = (float*)d_ws;
  float* xz  = ws + XZ_OFF;
  float* xs  = ws + XS_OFF;
  float* dbl = ws + DBL_OFF;
  float* ap  = ws + AP_OFF;
  float* ps  = ws + PS_OFF;
  float* yc  = ap;  // alias: aprod dead after pass2

  k_gemm_in<<<dim3(512, 4), 256, 0, stream>>>(x, W_in, xz);
  k_conv<<<dim3(256, 8, 2), 256, 0, stream>>>(xz, convw, convb, xs);
  k_gemm_x<<<dim3(2048), 256, 0, stream>>>(xs, W_x, dbl);
  k_scan1<<<dim3(NCH, 8, 2), 256, 0, stream>>>(xs, dbl, W_dt, b_dt, A_log, ap, ps);
  k_scan2<<<dim3(256), 256, 0, stream>>>(ap, ps);
  k_scan3<<<dim3(NCH, 8, 2), 256, 0, stream>>>(xz, xs, dbl, W_dt, b_dt, A_log, Dvec, ps);
  k_combine<<<dim3(16384), 256, 0, stream>>>(xs, yc);
  k_gemm_out<<<dim3(128, 2), 256, 0, stream>>>(yc, W_out, out);
}

// Round 5
// 510.347 us; speedup vs baseline: 1.2528x; 1.2528x over previous
//
#include <hip/hip_runtime.h>
#include <cstdint>
#include <cstddef>

// Sizes
#define LSEQ 4096
#define DI   512
#define NSTATE 16
#define TC 64     // scan chunk length
#define NCH 64    // number of chunks (LSEQ/TC)

// Workspace layout (floats):
//  xz   : [8][4096][1024]  = 33,554,432
//  xs   : [8][4096][512]   = 16,777,216  (becomes y in-place after scan pass3)
//  dbl  : [8][4096][48]    =  1,572,864
//  ap   : [8][64][512][16] =  4,194,304  (bf16 split bufs early; aprod; later ycomb)
//  ps   : [8][64][512][16] =  4,194,304  (pstate; becomes hinit in-place after pass2)
#define XZ_OFF  0
#define XS_OFF  33554432
#define DBL_OFF 50331648
#define AP_OFF  51904512
#define PS_OFF  56098816

typedef unsigned short u16;
typedef __attribute__((ext_vector_type(8))) short s8v;    // 8 bf16 (4 VGPR)
typedef __attribute__((ext_vector_type(4))) float f4v;    // 4 fp32 acc
typedef __attribute__((ext_vector_type(4))) unsigned int u32x4;

#ifndef __has_builtin
#define __has_builtin(x) 0
#endif
#if __has_builtin(__builtin_amdgcn_global_load_lds)
#define USE_GLL 1
#else
#define USE_GLL 0
#endif

__device__ __forceinline__ float silu_f(float v) { return v / (1.f + __expf(-v)); }
__device__ __forceinline__ float softplus_f(float v) {
  return fmaxf(v, 0.f) + log1pf(__expf(-fabsf(v)));
}
__device__ __forceinline__ u16 bf16_hi(float v) {   // RNE truncate to bf16
  unsigned u = __float_as_uint(v);
  return (u16)((u + 0x7fffu + ((u >> 16) & 1u)) >> 16);
}
__device__ __forceinline__ float bf16_f(u16 h) { return __uint_as_float(((unsigned)h) << 16); }

__device__ __forceinline__ void gld16(const u16* g, u16* l, int lane) {
#if USE_GLL
  __builtin_amdgcn_global_load_lds((const __attribute__((address_space(1))) void*)g,
                                   (__attribute__((address_space(3))) void*)l, 16, 0, 0);
#else
  *(u32x4*)(l + lane * 8) = *(const u32x4*)g;
#endif
}

// ---------------------------------------------------------------------------
// k_split: transpose fp32 [R][C] (batched) -> bf16 hi/lo [C][R]
// ---------------------------------------------------------------------------
__global__ __launch_bounds__(256) void k_split(const float* __restrict__ in,
                                               u16* __restrict__ oh,
                                               u16* __restrict__ ol,
                                               int R, int C) {
  __shared__ float tile[64][65];
  const size_t zoff = (size_t)blockIdx.z * R * C;
  in += zoff; oh += zoff; ol += zoff;
  const int c0 = blockIdx.x << 6, r0 = blockIdx.y << 6;
  const int tid = threadIdx.x;
  const int tx = tid & 63, ty = tid >> 6;
#pragma unroll
  for (int i = 0; i < 16; ++i) {
    const int r = ty + (i << 2);
    tile[r][tx] = in[(size_t)(r0 + r) * C + c0 + tx];
  }
  __syncthreads();
#pragma unroll
  for (int i = 0; i < 16; ++i) {
    const int cc = ty + (i << 2);
    const float v = tile[tx][cc];              // = in[r0+tx][c0+cc]
    const u16 h = bf16_hi(v);
    const size_t o = (size_t)(c0 + cc) * R + r0 + tx;
    oh[o] = h;
    ol[o] = bf16_hi(v - bf16_f(h));
  }
}

// ---------------------------------------------------------------------------
// Kernel 1: xz = z @ W_in via bf16x2-split MFMA (3-term), 128x128 tile, BK=32.
// A from xT (pre-transposed/split x, flip applied to source address),
// B from WinT ([n][k] bf16 hi/lo). LDS rows are 64B => every frag ds_read_b128
// covers a contiguous 1KB block (conflict-minimal).
// ---------------------------------------------------------------------------
__global__ __launch_bounds__(256) void k_gemm_in_mfma(const u16* __restrict__ xTh,
                                                      const u16* __restrict__ xTl,
                                                      const u16* __restrict__ Wh,
                                                      const u16* __restrict__ Wl,
                                                      float* __restrict__ xz) {
  __shared__ __attribute__((aligned(16))) u16 lds[4 * 128 * 32];  // Ah,Al,Bh,Bl
  u16* Ah = lds;
  u16* Al = lds + 4096;
  u16* Bh = lds + 8192;
  u16* Bl = lds + 12288;
  const int rt = blockIdx.x;            // 256 row tiles (128 rows each)
  const int nt = blockIdx.y;            // 8 col tiles (128 cols each)
  const int seq = rt >> 5, hl2 = rt & 31;
  const int b = seq & 1, dir = seq >> 1;
  const int tid = threadIdx.x;
  const int lane = tid & 63, wid = tid >> 6;
  const int wr = wid >> 1, wc = wid & 1;

  // staging: wave wid stages buffer wid (Ah/Al/Bh/Bl), 8 chunks of 1KB
  const u16* gsrc = (wid == 0) ? xTh : (wid == 1) ? xTl : (wid == 2) ? Wh : Wl;
  u16* ldst = lds + (wid << 12);
  size_t roff[8];
#pragma unroll
  for (int i = 0; i < 8; ++i) {
    const int r = (i << 4) + (lane >> 2);
    size_t off;
    if (wid < 2) {
      const int hl = (hl2 << 1) + (r >> 6), w = r & 63;
      const int hp = (dir & 2) ? 63 - hl : hl;
      const int wp = (dir & 1) ? 63 - w : w;
      off = ((size_t)((b << 12) + (hp << 6) + wp)) << 8;
    } else {
      off = ((size_t)((nt << 7) + r)) << 8;
    }
    roff[i] = off + ((lane & 3) << 3);
  }

  f4v acc[4][4];
  const f4v z4 = {0.f, 0.f, 0.f, 0.f};
#pragma unroll
  for (int m = 0; m < 4; ++m)
#pragma unroll
    for (int n = 0; n < 4; ++n) acc[m][n] = z4;

  const int fr = lane & 15;
  const int kg = (lane >> 4) << 3;

  for (int kc = 0; kc < 256; kc += 32) {
    __syncthreads();
#pragma unroll
    for (int i = 0; i < 8; ++i) gld16(gsrc + roff[i] + kc, ldst + (i << 9), lane);
    __syncthreads();
    s8v Afh[4], Afl[4], Bfh[4], Bfl[4];
#pragma unroll
    for (int m = 0; m < 4; ++m) {
      const int row = (wr << 6) + (m << 4) + fr;
      Afh[m] = *(const s8v*)&Ah[row * 32 + kg];
      Afl[m] = *(const s8v*)&Al[row * 32 + kg];
    }
#pragma unroll
    for (int n = 0; n < 4; ++n) {
      const int row = (wc << 6) + (n << 4) + fr;
      Bfh[n] = *(const s8v*)&Bh[row * 32 + kg];
      Bfl[n] = *(const s8v*)&Bl[row * 32 + kg];
    }
#pragma unroll
    for (int m = 0; m < 4; ++m)
#pragma unroll
      for (int n = 0; n < 4; ++n) {
        acc[m][n] = __builtin_amdgcn_mfma_f32_16x16x32_bf16(Afh[m], Bfh[n], acc[m][n], 0, 0, 0);
        acc[m][n] = __builtin_amdgcn_mfma_f32_16x16x32_bf16(Afh[m], Bfl[n], acc[m][n], 0, 0, 0);
        acc[m][n] = __builtin_amdgcn_mfma_f32_16x16x32_bf16(Afl[m], Bfh[n], acc[m][n], 0, 0, 0);
      }
  }
  // epilogue: C/D layout col=lane&15, row=(lane>>4)*4+reg
  const int rg = (lane >> 4) << 2;
  float* obase = xz + ((size_t)((rt << 7) + (wr << 6) + rg)) * 1024 + (nt << 7) + (wc << 6) + fr;
#pragma unroll
  for (int m = 0; m < 4; ++m)
#pragma unroll
    for (int n = 0; n < 4; ++n)
#pragma unroll
      for (int j = 0; j < 4; ++j)
        obase[(size_t)((m << 4) + j) * 1024 + (n << 4)] = acc[m][n][j];
}

// ---------------------------------------------------------------------------
// Kernel 2: depthwise causal conv(4) + bias + silu : xm (xz cols 0..511) -> xs
// ---------------------------------------------------------------------------
__global__ __launch_bounds__(256) void k_conv(const float* __restrict__ xz,
                                              const float* __restrict__ cw,
                                              const float* __restrict__ cb,
                                              float* __restrict__ xs) {
  const int t0  = blockIdx.x << 4;
  const int seq = blockIdx.y;
  const int d   = (blockIdx.z << 8) + threadIdx.x;
  const float* xm = xz + (size_t)seq * LSEQ * 1024 + d;
  const float w0 = cw[d * 4], w1 = cw[d * 4 + 1], w2 = cw[d * 4 + 2], w3 = cw[d * 4 + 3];
  const float bias = cb[d];
  float r0 = (t0 >= 3) ? xm[(size_t)(t0 - 3) * 1024] : 0.f;
  float r1 = (t0 >= 2) ? xm[(size_t)(t0 - 2) * 1024] : 0.f;
  float r2 = (t0 >= 1) ? xm[(size_t)(t0 - 1) * 1024] : 0.f;
  float* orow = xs + ((size_t)seq * LSEQ + t0) * DI + d;
#pragma unroll
  for (int i = 0; i < 16; ++i) {
    const float r3 = xm[(size_t)(t0 + i) * 1024];
    const float v = fmaf(w0, r0, fmaf(w1, r1, fmaf(w2, r2, fmaf(w3, r3, bias))));
    orow[(size_t)i * DI] = silu_f(v);
    r0 = r1; r1 = r2; r2 = r3;
  }
}

// ---------------------------------------------------------------------------
// Kernel 3: dbl[row][0:48] = xs[row][:] @ W_x   (16 rows per block)
// ---------------------------------------------------------------------------
__global__ __launch_bounds__(256) void k_gemm_x(const float* __restrict__ xs,
                                                const float* __restrict__ Wx,
                                                float* __restrict__ dbl) {
  __shared__ float xsh[16][512];
  const int rb  = blockIdx.x;
  const int tid = threadIdx.x;
  const int r = tid >> 4, k4 = tid & 15;
  const float* src = xs + (size_t)rb * 16 * DI;
#pragma unroll
  for (int i = 0; i < 8; ++i) {
    const int k = (i << 6) + (k4 << 2);
    *(float4*)&xsh[r][k] = *(const float4*)&src[(size_t)r * DI + k];
  }
  __syncthreads();
  if (tid < 192) {
    const int col = tid % 48;
    const int rg  = tid / 48;
    float a0 = 0.f, a1 = 0.f, a2 = 0.f, a3 = 0.f;
    for (int k = 0; k < 512; k += 4) {
      float wv0 = Wx[(size_t)(k + 0) * 48 + col];
      float wv1 = Wx[(size_t)(k + 1) * 48 + col];
      float wv2 = Wx[(size_t)(k + 2) * 48 + col];
      float wv3 = Wx[(size_t)(k + 3) * 48 + col];
      const float4 x0 = *(const float4*)&xsh[rg * 4 + 0][k];
      const float4 x1 = *(const float4*)&xsh[rg * 4 + 1][k];
      const float4 x2 = *(const float4*)&xsh[rg * 4 + 2][k];
      const float4 x3 = *(const float4*)&xsh[rg * 4 + 3][k];
      a0 = fmaf(x0.x, wv0, fmaf(x0.y, wv1, fmaf(x0.z, wv2, fmaf(x0.w, wv3, a0))));
      a1 = fmaf(x1.x, wv0, fmaf(x1.y, wv1, fmaf(x1.z, wv2, fmaf(x1.w, wv3, a1))));
      a2 = fmaf(x2.x, wv0, fmaf(x2.y, wv1, fmaf(x2.z, wv2, fmaf(x2.w, wv3, a2))));
      a3 = fmaf(x3.x, wv0, fmaf(x3.y, wv1, fmaf(x3.z, wv2, fmaf(x3.w, wv3, a3))));
    }
    const size_t base = ((size_t)rb * 16 + rg * 4) * 48 + col;
    dbl[base] = a0; dbl[base + 48] = a1; dbl[base + 96] = a2; dbl[base + 144] = a3;
  }
}

// ---------------------------------------------------------------------------
// Kernel 4 (scan pass 1)
// ---------------------------------------------------------------------------
__global__ __launch_bounds__(256) void k_scan1(const float* __restrict__ xs,
                                               const float* __restrict__ dbl,
                                               const float* __restrict__ Wdt,
                                               const float* __restrict__ bdt,
                                               const float* __restrict__ Alog,
                                               float* __restrict__ aprod,
                                               float* __restrict__ pstate) {
  __shared__ float dsh[TC * 48];
  const int ch = blockIdx.x, seq = blockIdx.y;
  const int tid = threadIdx.x;
  const int d = (blockIdx.z << 8) + tid;
  const int t0 = ch << 6;
  const float* dsrc = dbl + ((size_t)seq * LSEQ + t0) * 48;
#pragma unroll
  for (int i = 0; i < 12; ++i) dsh[tid + (i << 8)] = dsrc[tid + (i << 8)];
  float wdt[16], Aa[16], st[16], P[16];
#pragma unroll
  for (int k = 0; k < 16; ++k) wdt[k] = Wdt[(size_t)k * DI + d];
  const float bd = bdt[d];
#pragma unroll
  for (int s = 0; s < NSTATE; ++s) {
    Aa[s] = -__expf(Alog[d * NSTATE + s]);
    st[s] = 0.f; P[s] = 1.f;
  }
  const float* xsrc = xs + ((size_t)seq * LSEQ + t0) * DI + d;
  __syncthreads();
  for (int t = 0; t < TC; ++t) {
    const float* dr = &dsh[t * 48];
    float dtp = bd;
#pragma unroll
    for (int k = 0; k < 16; ++k) dtp = fmaf(dr[k], wdt[k], dtp);
    const float dtv = softplus_f(dtp);
    const float u = dtv * xsrc[(size_t)t * DI];
#pragma unroll
    for (int s = 0; s < NSTATE; ++s) {
      const float a = __expf(dtv * Aa[s]);
      st[s] = fmaf(a, st[s], u * dr[16 + s]);
      P[s] *= a;
    }
  }
  float* ap = aprod  + (((size_t)seq * NCH + ch) * DI + d) * NSTATE;
  float* pp = pstate + (((size_t)seq * NCH + ch) * DI + d) * NSTATE;
#pragma unroll
  for (int s = 0; s < NSTATE; s += 4) {
    *(float4*)&ap[s] = make_float4(P[s], P[s + 1], P[s + 2], P[s + 3]);
    *(float4*)&pp[s] = make_float4(st[s], st[s + 1], st[s + 2], st[s + 3]);
  }
}

// ---------------------------------------------------------------------------
// Kernel 5 (scan pass 2)
// ---------------------------------------------------------------------------
__global__ __launch_bounds__(256) void k_scan2(const float* __restrict__ aprod,
                                               float* __restrict__ pstate) {
  const int flat = blockIdx.x * 256 + threadIdx.x;
  const int seq = flat >> 13;
  const int rem = flat & 8191;
  const size_t stride = (size_t)DI * NSTATE;
  const size_t base = (size_t)seq * NCH * stride + rem;
  float h = 0.f;
  for (int ch = 0; ch < NCH; ++ch) {
    const size_t o = base + (size_t)ch * stride;
    const float a = aprod[o];
    const float bsum = pstate[o];
    pstate[o] = h;
    h = fmaf(a, h, bsum);
  }
}

// ---------------------------------------------------------------------------
// Kernel 6 (scan pass 3)
// ---------------------------------------------------------------------------
__global__ __launch_bounds__(256) void k_scan3(const float* __restrict__ xz,
                                               float* __restrict__ xs,
                                               const float* __restrict__ dbl,
                                               const float* __restrict__ Wdt,
                                               const float* __restrict__ bdt,
                                               const float* __restrict__ Alog,
                                               const float* __restrict__ Dv,
                                               const float* __restrict__ hinit) {
  __shared__ float dsh[TC * 48];
  const int ch = blockIdx.x, seq = blockIdx.y;
  const int tid = threadIdx.x;
  const int d = (blockIdx.z << 8) + tid;
  const int t0 = ch << 6;
  const float* dsrc = dbl + ((size_t)seq * LSEQ + t0) * 48;
#pragma unroll
  for (int i = 0; i < 12; ++i) dsh[tid + (i << 8)] = dsrc[tid + (i << 8)];
  float wdt[16], Aa[16], st[16];
#pragma unroll
  for (int k = 0; k < 16; ++k) wdt[k] = Wdt[(size_t)k * DI + d];
  const float bd = bdt[d];
  const float Dp = Dv[d];
  const float* hp = hinit + (((size_t)seq * NCH + ch) * DI + d) * NSTATE;
#pragma unroll
  for (int s = 0; s < NSTATE; ++s) {
    Aa[s] = -__expf(Alog[d * NSTATE + s]);
    st[s] = hp[s];
  }
  float* xrow = xs + ((size_t)seq * LSEQ + t0) * DI + d;
  const float* grow = xz + ((size_t)seq * LSEQ + t0) * 1024 + 512 + d;
  __syncthreads();
  for (int t = 0; t < TC; ++t) {
    const float* dr = &dsh[t * 48];
    float dtp = bd;
#pragma unroll
    for (int k = 0; k < 16; ++k) dtp = fmaf(dr[k], wdt[k], dtp);
    const float dtv = softplus_f(dtp);
    const float xsv = xrow[(size_t)t * DI];
    const float u = dtv * xsv;
    float y = 0.f;
#pragma unroll
    for (int s = 0; s < NSTATE; ++s) {
      const float a = __expf(dtv * Aa[s]);
      st[s] = fmaf(a, st[s], u * dr[16 + s]);
      y = fmaf(st[s], dr[32 + s], y);
    }
    y = fmaf(xsv, Dp, y);
    const float g = grow[(size_t)t * 1024];
    y *= silu_f(g);
    xrow[(size_t)t * DI] = y;
  }
}

// ---------------------------------------------------------------------------
// Kernel 7: combine 4 directions
// ---------------------------------------------------------------------------
__global__ __launch_bounds__(256) void k_combine(const float* __restrict__ y,
                                                 float* __restrict__ yc) {
  const int flat = blockIdx.x * 256 + threadIdx.x;
  const int d = flat & 511;
  const int t = (flat >> 9) & 4095;
  const int b = flat >> 21;
  const int h = t >> 6, w = t & 63;
  const int t1 = (h << 6) | (63 - w);
  const int t2 = ((63 - h) << 6) | w;
  const int t3 = ((63 - h) << 6) | (63 - w);
  const float v = y[((size_t)(0 + b) * LSEQ + t)  * DI + d] +
                  y[((size_t)(2 + b) * LSEQ + t1) * DI + d] +
                  y[((size_t)(4 + b) * LSEQ + t2) * DI + d] +
                  y[((size_t)(6 + b) * LSEQ + t3) * DI + d];
  yc[flat] = 0.25f * v;
}

// ---------------------------------------------------------------------------
// Kernel 8: out[b][c][t] = yc[b][t][:] @ W_out[:][c]
// ---------------------------------------------------------------------------
__global__ __launch_bounds__(256) void k_gemm_out(const float* __restrict__ yc,
                                                  const float* __restrict__ Wout,
                                                  float* __restrict__ out) {
  __shared__ float smem[64 * 64 + 64 * 128];
  float* Ash = smem;
  float* Bsh = smem + 64 * 64;
  const int bt = blockIdx.x;
  const int b = bt >> 6, tt = bt & 63;
  const int t0 = tt << 6;
  const int c0 = blockIdx.y << 7;
  const int tid = threadIdx.x;
  const int rq = tid >> 4, k4 = tid & 15;
  const int cq = tid & 31, dr8 = tid >> 5;
  const int tx = tid & 31, ty = tid >> 5;
  float acc[8][4];
#pragma unroll
  for (int i = 0; i < 8; ++i)
#pragma unroll
    for (int j = 0; j < 4; ++j) acc[i][j] = 0.f;

  for (int kc = 0; kc < 512; kc += 64) {
#pragma unroll
    for (int i = 0; i < 4; ++i) {
      const int row = rq + (i << 4);
      const float4 v = *(const float4*)&yc[((size_t)b * LSEQ + t0 + row) * DI + kc + (k4 << 2)];
      *(float4*)&Ash[row * 64 + (k4 << 2)] = v;
    }
#pragma unroll
    for (int i = 0; i < 8; ++i) {
      const int kk = dr8 + (i << 3);
      *(float4*)&Bsh[kk * 128 + cq * 4] =
          *(const float4*)&Wout[(size_t)(kc + kk) * 256 + c0 + cq * 4];
    }
    __syncthreads();
#pragma unroll
    for (int kk = 0; kk < 64; ++kk) {
      const float4 bv = *(const float4*)&Bsh[kk * 128 + tx * 4];
      const float br[4] = {bv.x, bv.y, bv.z, bv.w};
#pragma unroll
      for (int i = 0; i < 8; ++i) {
        const float av = Ash[(ty * 8 + i) * 64 + kk];
#pragma unroll
        for (int j = 0; j < 4; ++j) acc[i][j] = fmaf(av, br[j], acc[i][j]);
      }
    }
    __syncthreads();
  }
  float* Clds = smem;
  __syncthreads();
#pragma unroll
  for (int i = 0; i < 8; ++i)
#pragma unroll
    for (int j = 0; j < 4; ++j) Clds[(tx * 4 + j) * 65 + ty * 8 + i] = acc[i][j];
  __syncthreads();
#pragma unroll
  for (int rr = 0; rr < 32; ++rr) {
    const int idx = rr * 256 + tid;
    const int cl = idx >> 6, tl = idx & 63;
    out[((size_t)b * 256 + c0 + cl) * LSEQ + t0 + tl] = Clds[cl * 65 + tl];
  }
}

// ---------------------------------------------------------------------------
extern "C" void kernel_launch(void* const* d_in, const int* in_sizes, int n_in,
                              void* d_out, int out_size, void* d_ws, size_t ws_size,
                              hipStream_t stream) {
  const float* x     = (const float*)d_in[0];
  const float* W_in  = (const float*)d_in[1];
  const float* convw = (const float*)d_in[2];
  const float* convb = (const float*)d_in[3];
  const float* W_x   = (const float*)d_in[4];
  const float* W_dt  = (const float*)d_in[5];
  const float* b_dt  = (const float*)d_in[6];
  const float* A_log = (const float*)d_in[7];
  const float* Dvec  = (const float*)d_in[8];
  const float* W_out = (const float*)d_in[9];
  float* out = (float*)d_out;

  float* ws  = (float*)d_ws;
  float* xz  = ws + XZ_OFF;
  float* xs  = ws + XS_OFF;
  float* dbl = ws + DBL_OFF;
  float* ap  = ws + AP_OFF;
  float* ps  = ws + PS_OFF;
  float* yc  = ap;  // alias: aprod dead after pass2

  // bf16-split buffers alias the ap region (dead until scan1)
  u16* xTh   = (u16*)ap;                 // [2][4096][256] bf16
  u16* xTl   = xTh + 2097152;
  u16* WinTh = xTl + 2097152;            // [1024][256] bf16
  u16* WinTl = WinTh + 262144;

  k_split<<<dim3(64, 4, 2), 256, 0, stream>>>(x, xTh, xTl, 256, 4096);
  k_split<<<dim3(16, 4, 1), 256, 0, stream>>>(W_in, WinTh, WinTl, 256, 1024);
  k_gemm_in_mfma<<<dim3(256, 8), 256, 0, stream>>>(xTh, xTl, WinTh, WinTl, xz);
  k_conv<<<dim3(256, 8, 2), 256, 0, stream>>>(xz, convw, convb, xs);
  k_gemm_x<<<dim3(2048), 256, 0, stream>>>(xs, W_x, dbl);
  k_scan1<<<dim3(NCH, 8, 2), 256, 0, stream>>>(xs, dbl, W_dt, b_dt, A_log, ap, ps);
  k_scan2<<<dim3(256), 256, 0, stream>>>(ap, ps);
  k_scan3<<<dim3(NCH, 8, 2), 256, 0, stream>>>(xz, xs, dbl, W_dt, b_dt, A_log, Dvec, ps);
  k_combine<<<dim3(16384), 256, 0, stream>>>(xs, yc);
  k_gemm_out<<<dim3(128, 2), 256, 0, stream>>>(yc, W_out, out);
}

// Round 6
// 490.201 us; speedup vs baseline: 1.3043x; 1.0411x over previous
//
#include <hip/hip_runtime.h>
#include <cstdint>
#include <cstddef>

// Sizes
#define LSEQ 4096
#define DI   512
#define NSTATE 16
#define TC 64     // scan chunk length
#define NCH 64    // number of chunks (LSEQ/TC)

// Workspace layout (floats):
//  xz   : [8][4096][1024]  = 33,554,432
//  xs   : [8][4096][512]   = 16,777,216  (becomes y in-place after scan pass3)
//  dbl  : [8][4096][48]    =  1,572,864
//  ap   : [8][64][512][16] =  4,194,304  (bf16 split bufs early; aprod)
//  ps   : [8][64][512][16] =  4,194,304  (pstate; becomes hinit in-place after pass2)
#define XZ_OFF  0
#define XS_OFF  33554432
#define DBL_OFF 50331648
#define AP_OFF  51904512
#define PS_OFF  56098816

typedef unsigned short u16;
typedef __attribute__((ext_vector_type(8))) short s8v;    // 8 bf16 (4 VGPR)
typedef __attribute__((ext_vector_type(4))) float f4v;    // 4 fp32 acc
typedef __attribute__((ext_vector_type(4))) unsigned int u32x4;

#ifndef __has_builtin
#define __has_builtin(x) 0
#endif
#if __has_builtin(__builtin_amdgcn_global_load_lds)
#define USE_GLL 1
#else
#define USE_GLL 0
#endif

__device__ __forceinline__ float silu_f(float v) { return v / (1.f + __expf(-v)); }
__device__ __forceinline__ float softplus_f(float v) {
  return fmaxf(v, 0.f) + log1pf(__expf(-fabsf(v)));
}
__device__ __forceinline__ u16 bf16_hi(float v) {   // RNE truncate to bf16
  unsigned u = __float_as_uint(v);
  return (u16)((u + 0x7fffu + ((u >> 16) & 1u)) >> 16);
}
__device__ __forceinline__ float bf16_f(u16 h) { return __uint_as_float(((unsigned)h) << 16); }

__device__ __forceinline__ void gld16(const u16* g, u16* l, int lane) {
#if USE_GLL
  __builtin_amdgcn_global_load_lds((const __attribute__((address_space(1))) void*)g,
                                   (__attribute__((address_space(3))) void*)l, 16, 0, 0);
#else
  *(u32x4*)(l + lane * 8) = *(const u32x4*)g;
#endif
}

// powers r^1..r^16 via log-depth ladder (15 muls, depth ~4)
__device__ __forceinline__ void pow_ladder(float r, float* a) {
  const float r2 = r * r, r4 = r2 * r2, r8 = r4 * r4;
  a[0] = r;        a[1] = r2;       a[2] = r2 * r;   a[3] = r4;
  a[4] = r4 * r;   a[5] = r4 * r2;  a[6] = r4 * a[2]; a[7] = r8;
  a[8] = r8 * r;   a[9] = r8 * r2;  a[10] = r8 * a[2]; a[11] = r8 * r4;
  a[12] = r8 * a[4]; a[13] = r8 * a[5]; a[14] = r8 * a[6]; a[15] = r8 * r8;
}

// ---------------------------------------------------------------------------
// k_split: transpose fp32 [R][C] (batched) -> bf16 hi/lo [C][R]
// ---------------------------------------------------------------------------
__global__ __launch_bounds__(256) void k_split(const float* __restrict__ in,
                                               u16* __restrict__ oh,
                                               u16* __restrict__ ol,
                                               int R, int C) {
  __shared__ float tile[64][65];
  const size_t zoff = (size_t)blockIdx.z * R * C;
  in += zoff; oh += zoff; ol += zoff;
  const int c0 = blockIdx.x << 6, r0 = blockIdx.y << 6;
  const int tid = threadIdx.x;
  const int tx = tid & 63, ty = tid >> 6;
#pragma unroll
  for (int i = 0; i < 16; ++i) {
    const int r = ty + (i << 2);
    tile[r][tx] = in[(size_t)(r0 + r) * C + c0 + tx];
  }
  __syncthreads();
#pragma unroll
  for (int i = 0; i < 16; ++i) {
    const int cc = ty + (i << 2);
    const float v = tile[tx][cc];              // = in[r0+tx][c0+cc]
    const u16 h = bf16_hi(v);
    const size_t o = (size_t)(c0 + cc) * R + r0 + tx;
    oh[o] = h;
    ol[o] = bf16_hi(v - bf16_f(h));
  }
}

// ---------------------------------------------------------------------------
// Kernel 1: xz = z @ W_in via bf16x2-split MFMA (3-term), 128x128 tile, BK=32.
// ---------------------------------------------------------------------------
__global__ __launch_bounds__(256) void k_gemm_in_mfma(const u16* __restrict__ xTh,
                                                      const u16* __restrict__ xTl,
                                                      const u16* __restrict__ Wh,
                                                      const u16* __restrict__ Wl,
                                                      float* __restrict__ xz) {
  __shared__ __attribute__((aligned(16))) u16 lds[4 * 128 * 32];  // Ah,Al,Bh,Bl
  u16* Ah = lds;
  u16* Al = lds + 4096;
  u16* Bh = lds + 8192;
  u16* Bl = lds + 12288;
  const int rt = blockIdx.x;            // 256 row tiles (128 rows each)
  const int nt = blockIdx.y;            // 8 col tiles (128 cols each)
  const int seq = rt >> 5, hl2 = rt & 31;
  const int b = seq & 1, dir = seq >> 1;
  const int tid = threadIdx.x;
  const int lane = tid & 63, wid = tid >> 6;
  const int wr = wid >> 1, wc = wid & 1;

  const u16* gsrc = (wid == 0) ? xTh : (wid == 1) ? xTl : (wid == 2) ? Wh : Wl;
  u16* ldst = lds + (wid << 12);
  size_t roff[8];
#pragma unroll
  for (int i = 0; i < 8; ++i) {
    const int r = (i << 4) + (lane >> 2);
    size_t off;
    if (wid < 2) {
      const int hl = (hl2 << 1) + (r >> 6), w = r & 63;
      const int hp = (dir & 2) ? 63 - hl : hl;
      const int wp = (dir & 1) ? 63 - w : w;
      off = ((size_t)((b << 12) + (hp << 6) + wp)) << 8;
    } else {
      off = ((size_t)((nt << 7) + r)) << 8;
    }
    roff[i] = off + ((lane & 3) << 3);
  }

  f4v acc[4][4];
  const f4v z4 = {0.f, 0.f, 0.f, 0.f};
#pragma unroll
  for (int m = 0; m < 4; ++m)
#pragma unroll
    for (int n = 0; n < 4; ++n) acc[m][n] = z4;

  const int fr = lane & 15;
  const int kg = (lane >> 4) << 3;

  for (int kc = 0; kc < 256; kc += 32) {
    __syncthreads();
#pragma unroll
    for (int i = 0; i < 8; ++i) gld16(gsrc + roff[i] + kc, ldst + (i << 9), lane);
    __syncthreads();
    s8v Afh[4], Afl[4], Bfh[4], Bfl[4];
#pragma unroll
    for (int m = 0; m < 4; ++m) {
      const int row = (wr << 6) + (m << 4) + fr;
      Afh[m] = *(const s8v*)&Ah[row * 32 + kg];
      Afl[m] = *(const s8v*)&Al[row * 32 + kg];
    }
#pragma unroll
    for (int n = 0; n < 4; ++n) {
      const int row = (wc << 6) + (n << 4) + fr;
      Bfh[n] = *(const s8v*)&Bh[row * 32 + kg];
      Bfl[n] = *(const s8v*)&Bl[row * 32 + kg];
    }
#pragma unroll
    for (int m = 0; m < 4; ++m)
#pragma unroll
      for (int n = 0; n < 4; ++n) {
        acc[m][n] = __builtin_amdgcn_mfma_f32_16x16x32_bf16(Afh[m], Bfh[n], acc[m][n], 0, 0, 0);
        acc[m][n] = __builtin_amdgcn_mfma_f32_16x16x32_bf16(Afh[m], Bfl[n], acc[m][n], 0, 0, 0);
        acc[m][n] = __builtin_amdgcn_mfma_f32_16x16x32_bf16(Afl[m], Bfh[n], acc[m][n], 0, 0, 0);
      }
  }
  const int rg = (lane >> 4) << 2;
  float* obase = xz + ((size_t)((rt << 7) + (wr << 6) + rg)) * 1024 + (nt << 7) + (wc << 6) + fr;
#pragma unroll
  for (int m = 0; m < 4; ++m)
#pragma unroll
    for (int n = 0; n < 4; ++n)
#pragma unroll
      for (int j = 0; j < 4; ++j)
        obase[(size_t)((m << 4) + j) * 1024 + (n << 4)] = acc[m][n][j];
}

// ---------------------------------------------------------------------------
// Kernel 2: depthwise causal conv(4) + bias + silu : xm (xz cols 0..511) -> xs
// ---------------------------------------------------------------------------
__global__ __launch_bounds__(256) void k_conv(const float* __restrict__ xz,
                                              const float* __restrict__ cw,
                                              const float* __restrict__ cb,
                                              float* __restrict__ xs) {
  const int t0  = blockIdx.x << 4;
  const int seq = blockIdx.y;
  const int d   = (blockIdx.z << 8) + threadIdx.x;
  const float* xm = xz + (size_t)seq * LSEQ * 1024 + d;
  const float w0 = cw[d * 4], w1 = cw[d * 4 + 1], w2 = cw[d * 4 + 2], w3 = cw[d * 4 + 3];
  const float bias = cb[d];
  float r0 = (t0 >= 3) ? xm[(size_t)(t0 - 3) * 1024] : 0.f;
  float r1 = (t0 >= 2) ? xm[(size_t)(t0 - 2) * 1024] : 0.f;
  float r2 = (t0 >= 1) ? xm[(size_t)(t0 - 1) * 1024] : 0.f;
  float* orow = xs + ((size_t)seq * LSEQ + t0) * DI + d;
#pragma unroll
  for (int i = 0; i < 16; ++i) {
    const float r3 = xm[(size_t)(t0 + i) * 1024];
    const float v = fmaf(w0, r0, fmaf(w1, r1, fmaf(w2, r2, fmaf(w3, r3, bias))));
    orow[(size_t)i * DI] = silu_f(v);
    r0 = r1; r1 = r2; r2 = r3;
  }
}

// ---------------------------------------------------------------------------
// Kernel 3: dbl[row][0:48] = xs[row][:] @ W_x   (16 rows per block)
// ---------------------------------------------------------------------------
__global__ __launch_bounds__(256) void k_gemm_x(const float* __restrict__ xs,
                                                const float* __restrict__ Wx,
                                                float* __restrict__ dbl) {
  __shared__ float xsh[16][512];
  const int rb  = blockIdx.x;
  const int tid = threadIdx.x;
  const int r = tid >> 4, k4 = tid & 15;
  const float* src = xs + (size_t)rb * 16 * DI;
#pragma unroll
  for (int i = 0; i < 8; ++i) {
    const int k = (i << 6) + (k4 << 2);
    *(float4*)&xsh[r][k] = *(const float4*)&src[(size_t)r * DI + k];
  }
  __syncthreads();
  if (tid < 192) {
    const int col = tid % 48;
    const int rg  = tid / 48;
    float a0 = 0.f, a1 = 0.f, a2 = 0.f, a3 = 0.f;
    for (int k = 0; k < 512; k += 4) {
      float wv0 = Wx[(size_t)(k + 0) * 48 + col];
      float wv1 = Wx[(size_t)(k + 1) * 48 + col];
      float wv2 = Wx[(size_t)(k + 2) * 48 + col];
      float wv3 = Wx[(size_t)(k + 3) * 48 + col];
      const float4 x0 = *(const float4*)&xsh[rg * 4 + 0][k];
      const float4 x1 = *(const float4*)&xsh[rg * 4 + 1][k];
      const float4 x2 = *(const float4*)&xsh[rg * 4 + 2][k];
      const float4 x3 = *(const float4*)&xsh[rg * 4 + 3][k];
      a0 = fmaf(x0.x, wv0, fmaf(x0.y, wv1, fmaf(x0.z, wv2, fmaf(x0.w, wv3, a0))));
      a1 = fmaf(x1.x, wv0, fmaf(x1.y, wv1, fmaf(x1.z, wv2, fmaf(x1.w, wv3, a1))));
      a2 = fmaf(x2.x, wv0, fmaf(x2.y, wv1, fmaf(x2.z, wv2, fmaf(x2.w, wv3, a2))));
      a3 = fmaf(x3.x, wv0, fmaf(x3.y, wv1, fmaf(x3.z, wv2, fmaf(x3.w, wv3, a3))));
    }
    const size_t base = ((size_t)rb * 16 + rg * 4) * 48 + col;
    dbl[base] = a0; dbl[base + 48] = a1; dbl[base + 96] = a2; dbl[base + 144] = a3;
  }
}

// ---------------------------------------------------------------------------
// Kernel 4 (scan pass 1): fast path exploits A[s] == -(s+1) (verified at
// runtime per-thread from A_log; wave-uniform branch) => one exp + pow ladder
// per t, and P[s] = Rprod^(s+1) at chunk end.
// ---------------------------------------------------------------------------
__global__ __launch_bounds__(256) void k_scan1(const float* __restrict__ xs,
                                               const float* __restrict__ dbl,
                                               const float* __restrict__ Wdt,
                                               const float* __restrict__ bdt,
                                               const float* __restrict__ Alog,
                                               float* __restrict__ aprod,
                                               float* __restrict__ pstate) {
  __shared__ float dsh[TC * 48];
  const int ch = blockIdx.x, seq = blockIdx.y;
  const int tid = threadIdx.x;
  const int d = (blockIdx.z << 8) + tid;
  const int t0 = ch << 6;
  const float* dsrc = dbl + ((size_t)seq * LSEQ + t0) * 48;
#pragma unroll
  for (int i = 0; i < 12; ++i) dsh[tid + (i << 8)] = dsrc[tid + (i << 8)];
  float wdt[16], Aa[16], st[16], P[16];
#pragma unroll
  for (int k = 0; k < 16; ++k) wdt[k] = Wdt[(size_t)k * DI + d];
  const float bd = bdt[d];
  bool fast = true;
#pragma unroll
  for (int s = 0; s < NSTATE; ++s) {
    const float Av = __expf(Alog[d * NSTATE + s]);
    Aa[s] = -Av;
    fast = fast && (fabsf(Av - (float)(s + 1)) < 1e-3f);
    st[s] = 0.f; P[s] = 1.f;
  }
  const float* xsrc = xs + ((size_t)seq * LSEQ + t0) * DI + d;
  __syncthreads();
  if (fast) {
    float Rp = 1.f;
    for (int t = 0; t < TC; ++t) {
      const float* dr = &dsh[t * 48];
      float dtp = bd;
#pragma unroll
      for (int k = 0; k < 16; ++k) dtp = fmaf(dr[k], wdt[k], dtp);
      const float dtv = softplus_f(dtp);
      const float u = dtv * xsrc[(size_t)t * DI];
      const float r = __expf(-dtv);
      float a[16];
      pow_ladder(r, a);
      Rp *= r;
#pragma unroll
      for (int s = 0; s < NSTATE; ++s) st[s] = fmaf(a[s], st[s], u * dr[16 + s]);
    }
    pow_ladder(Rp, P);
  } else {
    for (int t = 0; t < TC; ++t) {
      const float* dr = &dsh[t * 48];
      float dtp = bd;
#pragma unroll
      for (int k = 0; k < 16; ++k) dtp = fmaf(dr[k], wdt[k], dtp);
      const float dtv = softplus_f(dtp);
      const float u = dtv * xsrc[(size_t)t * DI];
#pragma unroll
      for (int s = 0; s < NSTATE; ++s) {
        const float a = __expf(dtv * Aa[s]);
        st[s] = fmaf(a, st[s], u * dr[16 + s]);
        P[s] *= a;
      }
    }
  }
  float* ap = aprod  + (((size_t)seq * NCH + ch) * DI + d) * NSTATE;
  float* pp = pstate + (((size_t)seq * NCH + ch) * DI + d) * NSTATE;
#pragma unroll
  for (int s = 0; s < NSTATE; s += 4) {
    *(float4*)&ap[s] = make_float4(P[s], P[s + 1], P[s + 2], P[s + 3]);
    *(float4*)&pp[s] = make_float4(st[s], st[s + 1], st[s + 2], st[s + 3]);
  }
}

// ---------------------------------------------------------------------------
// Kernel 5 (scan pass 2)
// ---------------------------------------------------------------------------
__global__ __launch_bounds__(256) void k_scan2(const float* __restrict__ aprod,
                                               float* __restrict__ pstate) {
  const int flat = blockIdx.x * 256 + threadIdx.x;
  const int seq = flat >> 13;
  const int rem = flat & 8191;
  const size_t stride = (size_t)DI * NSTATE;
  const size_t base = (size_t)seq * NCH * stride + rem;
  float h = 0.f;
  for (int ch = 0; ch < NCH; ++ch) {
    const size_t o = base + (size_t)ch * stride;
    const float a = aprod[o];
    const float bsum = pstate[o];
    pstate[o] = h;
    h = fmaf(a, h, bsum);
  }
}

// ---------------------------------------------------------------------------
// Kernel 6 (scan pass 3): same fast path; y written over xs in place.
// ---------------------------------------------------------------------------
__global__ __launch_bounds__(256) void k_scan3(const float* __restrict__ xz,
                                               float* __restrict__ xs,
                                               const float* __restrict__ dbl,
                                               const float* __restrict__ Wdt,
                                               const float* __restrict__ bdt,
                                               const float* __restrict__ Alog,
                                               const float* __restrict__ Dv,
                                               const float* __restrict__ hinit) {
  __shared__ float dsh[TC * 48];
  const int ch = blockIdx.x, seq = blockIdx.y;
  const int tid = threadIdx.x;
  const int d = (blockIdx.z << 8) + tid;
  const int t0 = ch << 6;
  const float* dsrc = dbl + ((size_t)seq * LSEQ + t0) * 48;
#pragma unroll
  for (int i = 0; i < 12; ++i) dsh[tid + (i << 8)] = dsrc[tid + (i << 8)];
  float wdt[16], Aa[16], st[16];
#pragma unroll
  for (int k = 0; k < 16; ++k) wdt[k] = Wdt[(size_t)k * DI + d];
  const float bd = bdt[d];
  const float Dp = Dv[d];
  const float* hp = hinit + (((size_t)seq * NCH + ch) * DI + d) * NSTATE;
  bool fast = true;
#pragma unroll
  for (int s = 0; s < NSTATE; ++s) {
    const float Av = __expf(Alog[d * NSTATE + s]);
    Aa[s] = -Av;
    fast = fast && (fabsf(Av - (float)(s + 1)) < 1e-3f);
    st[s] = hp[s];
  }
  float* xrow = xs + ((size_t)seq * LSEQ + t0) * DI + d;
  const float* grow = xz + ((size_t)seq * LSEQ + t0) * 1024 + 512 + d;
  __syncthreads();
  if (fast) {
    for (int t = 0; t < TC; ++t) {
      const float* dr = &dsh[t * 48];
      float dtp = bd;
#pragma unroll
      for (int k = 0; k < 16; ++k) dtp = fmaf(dr[k], wdt[k], dtp);
      const float dtv = softplus_f(dtp);
      const float xsv = xrow[(size_t)t * DI];
      const float u = dtv * xsv;
      const float r = __expf(-dtv);
      float a[16];
      pow_ladder(r, a);
      float y = 0.f;
#pragma unroll
      for (int s = 0; s < NSTATE; ++s) {
        st[s] = fmaf(a[s], st[s], u * dr[16 + s]);
        y = fmaf(st[s], dr[32 + s], y);
      }
      y = fmaf(xsv, Dp, y);
      const float g = grow[(size_t)t * 1024];
      y *= silu_f(g);
      xrow[(size_t)t * DI] = y;
    }
  } else {
    for (int t = 0; t < TC; ++t) {
      const float* dr = &dsh[t * 48];
      float dtp = bd;
#pragma unroll
      for (int k = 0; k < 16; ++k) dtp = fmaf(dr[k], wdt[k], dtp);
      const float dtv = softplus_f(dtp);
      const float xsv = xrow[(size_t)t * DI];
      const float u = dtv * xsv;
      float y = 0.f;
#pragma unroll
      for (int s = 0; s < NSTATE; ++s) {
        const float a = __expf(dtv * Aa[s]);
        st[s] = fmaf(a, st[s], u * dr[16 + s]);
        y = fmaf(st[s], dr[32 + s], y);
      }
      y = fmaf(xsv, Dp, y);
      const float g = grow[(size_t)t * 1024];
      y *= silu_f(g);
      xrow[(size_t)t * DI] = y;
    }
  }
}

// ---------------------------------------------------------------------------
// Kernel 8 (fused combine + out-proj): A row = avg of 4 unflipped y rows,
// computed while staging into LDS. out[b][c][t] = A[t][:] @ W_out[:][c].
// ---------------------------------------------------------------------------
__global__ __launch_bounds__(256) void k_gemm_out(const float* __restrict__ y,
                                                  const float* __restrict__ Wout,
                                                  float* __restrict__ out) {
  __shared__ float smem[64 * 64 + 64 * 128];
  float* Ash = smem;
  float* Bsh = smem + 64 * 64;
  const int bt = blockIdx.x;
  const int b = bt >> 6, tt = bt & 63;
  const int t0 = tt << 6;
  const int c0 = blockIdx.y << 7;
  const int tid = threadIdx.x;
  const int rq = tid >> 4, k4 = tid & 15;
  const int cq = tid & 31, dr8 = tid >> 5;
  const int tx = tid & 31, ty = tid >> 5;
  const int hf = (63 - tt) << 6;   // flipped h base
  float acc[8][4];
#pragma unroll
  for (int i = 0; i < 8; ++i)
#pragma unroll
    for (int j = 0; j < 4; ++j) acc[i][j] = 0.f;

  for (int kc = 0; kc < 512; kc += 64) {
#pragma unroll
    for (int i = 0; i < 4; ++i) {
      const int row = rq + (i << 4);
      const int wf = 63 - row;
      const size_t off = kc + (k4 << 2);
      const float4 v0 = *(const float4*)&y[(((size_t)(0 + b) * LSEQ) + t0 + row) * DI + off];
      const float4 v1 = *(const float4*)&y[(((size_t)(2 + b) * LSEQ) + t0 + wf)  * DI + off];
      const float4 v2 = *(const float4*)&y[(((size_t)(4 + b) * LSEQ) + hf + row) * DI + off];
      const float4 v3 = *(const float4*)&y[(((size_t)(6 + b) * LSEQ) + hf + wf)  * DI + off];
      float4 av;
      av.x = 0.25f * (v0.x + v1.x + v2.x + v3.x);
      av.y = 0.25f * (v0.y + v1.y + v2.y + v3.y);
      av.z = 0.25f * (v0.z + v1.z + v2.z + v3.z);
      av.w = 0.25f * (v0.w + v1.w + v2.w + v3.w);
      *(float4*)&Ash[row * 64 + (k4 << 2)] = av;
    }
#pragma unroll
    for (int i = 0; i < 8; ++i) {
      const int kk = dr8 + (i << 3);
      *(float4*)&Bsh[kk * 128 + cq * 4] =
          *(const float4*)&Wout[(size_t)(kc + kk) * 256 + c0 + cq * 4];
    }
    __syncthreads();
#pragma unroll
    for (int kk = 0; kk < 64; ++kk) {
      const float4 bv = *(const float4*)&Bsh[kk * 128 + tx * 4];
      const float br[4] = {bv.x, bv.y, bv.z, bv.w};
#pragma unroll
      for (int i = 0; i < 8; ++i) {
        const float av = Ash[(ty * 8 + i) * 64 + kk];
#pragma unroll
        for (int j = 0; j < 4; ++j) acc[i][j] = fmaf(av, br[j], acc[i][j]);
      }
    }
    __syncthreads();
  }
  float* Clds = smem;
  __syncthreads();
#pragma unroll
  for (int i = 0; i < 8; ++i)
#pragma unroll
    for (int j = 0; j < 4; ++j) Clds[(tx * 4 + j) * 65 + ty * 8 + i] = acc[i][j];
  __syncthreads();
#pragma unroll
  for (int rr = 0; rr < 32; ++rr) {
    const int idx = rr * 256 + tid;
    const int cl = idx >> 6, tl = idx & 63;
    out[((size_t)b * 256 + c0 + cl) * LSEQ + t0 + tl] = Clds[cl * 65 + tl];
  }
}

// ---------------------------------------------------------------------------
extern "C" void kernel_launch(void* const* d_in, const int* in_sizes, int n_in,
                              void* d_out, int out_size, void* d_ws, size_t ws_size,
                              hipStream_t stream) {
  const float* x     = (const float*)d_in[0];
  const float* W_in  = (const float*)d_in[1];
  const float* convw = (const float*)d_in[2];
  const float* convb = (const float*)d_in[3];
  const float* W_x   = (const float*)d_in[4];
  const float* W_dt  = (const float*)d_in[5];
  const float* b_dt  = (const float*)d_in[6];
  const float* A_log = (const float*)d_in[7];
  const float* Dvec  = (const float*)d_in[8];
  const float* W_out = (const float*)d_in[9];
  float* out = (float*)d_out;

  float* ws  = (float*)d_ws;
  float* xz  = ws + XZ_OFF;
  float* xs  = ws + XS_OFF;
  float* dbl = ws + DBL_OFF;
  float* ap  = ws + AP_OFF;
  float* ps  = ws + PS_OFF;

  // bf16-split buffers alias the ap region (dead until scan1)
  u16* xTh   = (u16*)ap;                 // [2][4096][256] bf16
  u16* xTl   = xTh + 2097152;
  u16* WinTh = xTl + 2097152;            // [1024][256] bf16
  u16* WinTl = WinTh + 262144;

  k_split<<<dim3(64, 4, 2), 256, 0, stream>>>(x, xTh, xTl, 256, 4096);
  k_split<<<dim3(16, 4, 1), 256, 0, stream>>>(W_in, WinTh, WinTl, 256, 1024);
  k_gemm_in_mfma<<<dim3(256, 8), 256, 0, stream>>>(xTh, xTl, WinTh, WinTl, xz);
  k_conv<<<dim3(256, 8, 2), 256, 0, stream>>>(xz, convw, convb, xs);
  k_gemm_x<<<dim3(2048), 256, 0, stream>>>(xs, W_x, dbl);
  k_scan1<<<dim3(NCH, 8, 2), 256, 0, stream>>>(xs, dbl, W_dt, b_dt, A_log, ap, ps);
  k_scan2<<<dim3(256), 256, 0, stream>>>(ap, ps);
  k_scan3<<<dim3(NCH, 8, 2), 256, 0, stream>>>(xz, xs, dbl, W_dt, b_dt, A_log, Dvec, ps);
  k_gemm_out<<<dim3(128, 2), 256, 0, stream>>>(xs, W_out, out);
}

// Round 7
// 438.099 us; speedup vs baseline: 1.4594x; 1.1189x over previous
//
#include <hip/hip_runtime.h>
#include <cstdint>
#include <cstddef>

// Sizes
#define LSEQ 4096
#define DI   512
#define NSTATE 16
#define TC 32     // scan chunk length
#define NCH 128   // number of chunks (LSEQ/TC)

// Workspace layout (floats), total 54,263,808 fl = 217 MB:
//  xm   : [8][4096][512] @ 0          (dead after conv -> reused by ap/ps)
//  gate : [8][4096][512] @ 16,777,216
//  xs   : [8][4096][512] @ 33,554,432 (becomes y in-place after scan3)
//  dbl  : [8][4096][48]  @ 50,331,648
//  split: bf16 bufs      @ 51,904,512 (dead after gemm_in)
//  ap   : [8][128][512][16] @ 0          (aliases xm)
//  ps   : [8][128][512][16] @ 8,388,608  (aliases xm upper half)
#define XM_OFF    0
#define GATE_OFF  16777216
#define XS_OFF    33554432
#define DBL_OFF   50331648
#define SPLIT_OFF 51904512
#define AP_OFF    0
#define PS_OFF    8388608

typedef unsigned short u16;
typedef __attribute__((ext_vector_type(8))) short s8v;    // 8 bf16 (4 VGPR)
typedef __attribute__((ext_vector_type(4))) float f4v;    // 4 fp32 acc
typedef __attribute__((ext_vector_type(4))) unsigned int u32x4;

#ifndef __has_builtin
#define __has_builtin(x) 0
#endif
#if __has_builtin(__builtin_amdgcn_global_load_lds)
#define USE_GLL 1
#else
#define USE_GLL 0
#endif

__device__ __forceinline__ float silu_f(float v) {
  return v * __frcp_rn(1.f + __expf(-v));
}
__device__ __forceinline__ float softplus_f(float v) {
  // max(v,0) + log(1+exp(-|v|)); arg in (1,2], v_log-based, abs err ~1e-6
  return fmaxf(v, 0.f) + __logf(1.f + __expf(-fabsf(v)));
}
__device__ __forceinline__ u16 bf16_hi(float v) {   // RNE truncate to bf16
  unsigned u = __float_as_uint(v);
  return (u16)((u + 0x7fffu + ((u >> 16) & 1u)) >> 16);
}
__device__ __forceinline__ float bf16_f(u16 h) { return __uint_as_float(((unsigned)h) << 16); }

__device__ __forceinline__ void gld16(const u16* g, u16* l, int lane) {
#if USE_GLL
  __builtin_amdgcn_global_load_lds((const __attribute__((address_space(1))) void*)g,
                                   (__attribute__((address_space(3))) void*)l, 16, 0, 0);
#else
  *(u32x4*)(l + lane * 8) = *(const u32x4*)g;
#endif
}

// powers r^1..r^16 via log-depth ladder (15 muls, depth ~4)
__device__ __forceinline__ void pow_ladder(float r, float* a) {
  const float r2 = r * r, r4 = r2 * r2, r8 = r4 * r4;
  a[0] = r;        a[1] = r2;       a[2] = r2 * r;   a[3] = r4;
  a[4] = r4 * r;   a[5] = r4 * r2;  a[6] = r4 * a[2]; a[7] = r8;
  a[8] = r8 * r;   a[9] = r8 * r2;  a[10] = r8 * a[2]; a[11] = r8 * r4;
  a[12] = r8 * a[4]; a[13] = r8 * a[5]; a[14] = r8 * a[6]; a[15] = r8 * r8;
}

// ---------------------------------------------------------------------------
// k_split: transpose fp32 [R][C] (batched) -> bf16 hi/lo [C][R]
// ---------------------------------------------------------------------------
__global__ __launch_bounds__(256) void k_split(const float* __restrict__ in,
                                               u16* __restrict__ oh,
                                               u16* __restrict__ ol,
                                               int R, int C) {
  __shared__ float tile[64][65];
  const size_t zoff = (size_t)blockIdx.z * R * C;
  in += zoff; oh += zoff; ol += zoff;
  const int c0 = blockIdx.x << 6, r0 = blockIdx.y << 6;
  const int tid = threadIdx.x;
  const int tx = tid & 63, ty = tid >> 6;
#pragma unroll
  for (int i = 0; i < 16; ++i) {
    const int r = ty + (i << 2);
    tile[r][tx] = in[(size_t)(r0 + r) * C + c0 + tx];
  }
  __syncthreads();
#pragma unroll
  for (int i = 0; i < 16; ++i) {
    const int cc = ty + (i << 2);
    const float v = tile[tx][cc];              // = in[r0+tx][c0+cc]
    const u16 h = bf16_hi(v);
    const size_t o = (size_t)(c0 + cc) * R + r0 + tx;
    oh[o] = h;
    ol[o] = bf16_hi(v - bf16_f(h));
  }
}

// ---------------------------------------------------------------------------
// Kernel 1: [xm|gate] = z @ W_in via bf16x2-split MFMA, 128x128 tile, BK=32.
// nt<4 -> xm cols, nt>=4 -> gate cols (both stride-512 buffers).
// ---------------------------------------------------------------------------
__global__ __launch_bounds__(256) void k_gemm_in_mfma(const u16* __restrict__ xTh,
                                                      const u16* __restrict__ xTl,
                                                      const u16* __restrict__ Wh,
                                                      const u16* __restrict__ Wl,
                                                      float* __restrict__ xm,
                                                      float* __restrict__ gate) {
  __shared__ __attribute__((aligned(16))) u16 lds[4 * 128 * 32];  // Ah,Al,Bh,Bl
  u16* Ah = lds;
  u16* Al = lds + 4096;
  u16* Bh = lds + 8192;
  u16* Bl = lds + 12288;
  const int rt = blockIdx.x;            // 256 row tiles (128 rows each)
  const int nt = blockIdx.y;            // 8 col tiles (128 cols each)
  const int seq = rt >> 5, hl2 = rt & 31;
  const int b = seq & 1, dir = seq >> 1;
  const int tid = threadIdx.x;
  const int lane = tid & 63, wid = tid >> 6;
  const int wr = wid >> 1, wc = wid & 1;

  const u16* gsrc = (wid == 0) ? xTh : (wid == 1) ? xTl : (wid == 2) ? Wh : Wl;
  u16* ldst = lds + (wid << 12);
  size_t roff[8];
#pragma unroll
  for (int i = 0; i < 8; ++i) {
    const int r = (i << 4) + (lane >> 2);
    size_t off;
    if (wid < 2) {
      const int hl = (hl2 << 1) + (r >> 6), w = r & 63;
      const int hp = (dir & 2) ? 63 - hl : hl;
      const int wp = (dir & 1) ? 63 - w : w;
      off = ((size_t)((b << 12) + (hp << 6) + wp)) << 8;
    } else {
      off = ((size_t)((nt << 7) + r)) << 8;
    }
    roff[i] = off + ((lane & 3) << 3);
  }

  f4v acc[4][4];
  const f4v z4 = {0.f, 0.f, 0.f, 0.f};
#pragma unroll
  for (int m = 0; m < 4; ++m)
#pragma unroll
    for (int n = 0; n < 4; ++n) acc[m][n] = z4;

  const int fr = lane & 15;
  const int kg = (lane >> 4) << 3;

  for (int kc = 0; kc < 256; kc += 32) {
    __syncthreads();
#pragma unroll
    for (int i = 0; i < 8; ++i) gld16(gsrc + roff[i] + kc, ldst + (i << 9), lane);
    __syncthreads();
    s8v Afh[4], Afl[4], Bfh[4], Bfl[4];
#pragma unroll
    for (int m = 0; m < 4; ++m) {
      const int row = (wr << 6) + (m << 4) + fr;
      Afh[m] = *(const s8v*)&Ah[row * 32 + kg];
      Afl[m] = *(const s8v*)&Al[row * 32 + kg];
    }
#pragma unroll
    for (int n = 0; n < 4; ++n) {
      const int row = (wc << 6) + (n << 4) + fr;
      Bfh[n] = *(const s8v*)&Bh[row * 32 + kg];
      Bfl[n] = *(const s8v*)&Bl[row * 32 + kg];
    }
#pragma unroll
    for (int m = 0; m < 4; ++m)
#pragma unroll
      for (int n = 0; n < 4; ++n) {
        acc[m][n] = __builtin_amdgcn_mfma_f32_16x16x32_bf16(Afh[m], Bfh[n], acc[m][n], 0, 0, 0);
        acc[m][n] = __builtin_amdgcn_mfma_f32_16x16x32_bf16(Afh[m], Bfl[n], acc[m][n], 0, 0, 0);
        acc[m][n] = __builtin_amdgcn_mfma_f32_16x16x32_bf16(Afl[m], Bfh[n], acc[m][n], 0, 0, 0);
      }
  }
  const int rg = (lane >> 4) << 2;
  float* obuf = (nt & 4) ? gate : xm;
  const int ncol = (nt & 3) << 7;
  float* obase = obuf + ((size_t)((rt << 7) + (wr << 6) + rg)) * DI + ncol + (wc << 6) + fr;
#pragma unroll
  for (int m = 0; m < 4; ++m)
#pragma unroll
    for (int n = 0; n < 4; ++n)
#pragma unroll
      for (int j = 0; j < 4; ++j)
        obase[(size_t)((m << 4) + j) * DI + (n << 4)] = acc[m][n][j];
}

// ---------------------------------------------------------------------------
// Kernel 2: depthwise causal conv(4) + bias + silu : xm -> xs (stride 512)
// ---------------------------------------------------------------------------
__global__ __launch_bounds__(256) void k_conv(const float* __restrict__ xmb,
                                              const float* __restrict__ cw,
                                              const float* __restrict__ cb,
                                              float* __restrict__ xs) {
  const int t0  = blockIdx.x << 4;
  const int seq = blockIdx.y;
  const int d   = (blockIdx.z << 8) + threadIdx.x;
  const float* xm = xmb + (size_t)seq * LSEQ * DI + d;
  const float w0 = cw[d * 4], w1 = cw[d * 4 + 1], w2 = cw[d * 4 + 2], w3 = cw[d * 4 + 3];
  const float bias = cb[d];
  float r0 = (t0 >= 3) ? xm[(size_t)(t0 - 3) * DI] : 0.f;
  float r1 = (t0 >= 2) ? xm[(size_t)(t0 - 2) * DI] : 0.f;
  float r2 = (t0 >= 1) ? xm[(size_t)(t0 - 1) * DI] : 0.f;
  float* orow = xs + ((size_t)seq * LSEQ + t0) * DI + d;
#pragma unroll
  for (int i = 0; i < 16; ++i) {
    const float r3 = xm[(size_t)(t0 + i) * DI];
    const float v = fmaf(w0, r0, fmaf(w1, r1, fmaf(w2, r2, fmaf(w3, r3, bias))));
    orow[(size_t)i * DI] = silu_f(v);
    r0 = r1; r1 = r2; r2 = r3;
  }
}

// ---------------------------------------------------------------------------
// Kernel 3: dbl[row][0:48] = xs[row][:] @ W_x   (16 rows per block)
// ---------------------------------------------------------------------------
__global__ __launch_bounds__(256) void k_gemm_x(const float* __restrict__ xs,
                                                const float* __restrict__ Wx,
                                                float* __restrict__ dbl) {
  __shared__ float xsh[16][512];
  const int rb  = blockIdx.x;
  const int tid = threadIdx.x;
  const int r = tid >> 4, k4 = tid & 15;
  const float* src = xs + (size_t)rb * 16 * DI;
#pragma unroll
  for (int i = 0; i < 8; ++i) {
    const int k = (i << 6) + (k4 << 2);
    *(float4*)&xsh[r][k] = *(const float4*)&src[(size_t)r * DI + k];
  }
  __syncthreads();
  if (tid < 192) {
    const int col = tid % 48;
    const int rg  = tid / 48;
    float a0 = 0.f, a1 = 0.f, a2 = 0.f, a3 = 0.f;
    for (int k = 0; k < 512; k += 4) {
      float wv0 = Wx[(size_t)(k + 0) * 48 + col];
      float wv1 = Wx[(size_t)(k + 1) * 48 + col];
      float wv2 = Wx[(size_t)(k + 2) * 48 + col];
      float wv3 = Wx[(size_t)(k + 3) * 48 + col];
      const float4 x0 = *(const float4*)&xsh[rg * 4 + 0][k];
      const float4 x1 = *(const float4*)&xsh[rg * 4 + 1][k];
      const float4 x2 = *(const float4*)&xsh[rg * 4 + 2][k];
      const float4 x3 = *(const float4*)&xsh[rg * 4 + 3][k];
      a0 = fmaf(x0.x, wv0, fmaf(x0.y, wv1, fmaf(x0.z, wv2, fmaf(x0.w, wv3, a0))));
      a1 = fmaf(x1.x, wv0, fmaf(x1.y, wv1, fmaf(x1.z, wv2, fmaf(x1.w, wv3, a1))));
      a2 = fmaf(x2.x, wv0, fmaf(x2.y, wv1, fmaf(x2.z, wv2, fmaf(x2.w, wv3, a2))));
      a3 = fmaf(x3.x, wv0, fmaf(x3.y, wv1, fmaf(x3.z, wv2, fmaf(x3.w, wv3, a3))));
    }
    const size_t base = ((size_t)rb * 16 + rg * 4) * 48 + col;
    dbl[base] = a0; dbl[base + 48] = a1; dbl[base + 96] = a2; dbl[base + 144] = a3;
  }
}

// ---------------------------------------------------------------------------
// Kernel 4 (scan pass 1): TC=32 chunks; fast path uses A[s] == -(s+1)
// (verified per-thread from A_log) => one exp + pow ladder per t;
// P[s] = Rprod^(s+1) at chunk end.
// ---------------------------------------------------------------------------
__global__ __launch_bounds__(256) void k_scan1(const float* __restrict__ xs,
                                               const float* __restrict__ dbl,
                                               const float* __restrict__ Wdt,
                                               const float* __restrict__ bdt,
                                               const float* __restrict__ Alog,
                                               float* __restrict__ aprod,
                                               float* __restrict__ pstate) {
  __shared__ float dsh[TC * 48];
  const int ch = blockIdx.x, seq = blockIdx.y;
  const int tid = threadIdx.x;
  const int d = (blockIdx.z << 8) + tid;
  const int t0 = ch * TC;
  const float* dsrc = dbl + ((size_t)seq * LSEQ + t0) * 48;
#pragma unroll
  for (int i = 0; i < 6; ++i) dsh[tid + (i << 8)] = dsrc[tid + (i << 8)];
  float wdt[16], Aa[16], st[16], P[16];
#pragma unroll
  for (int k = 0; k < 16; ++k) wdt[k] = Wdt[(size_t)k * DI + d];
  const float bd = bdt[d];
  bool fast = true;
#pragma unroll
  for (int s = 0; s < NSTATE; ++s) {
    const float Av = __expf(Alog[d * NSTATE + s]);
    Aa[s] = -Av;
    fast = fast && (fabsf(Av - (float)(s + 1)) < 1e-3f);
    st[s] = 0.f; P[s] = 1.f;
  }
  const float* xsrc = xs + ((size_t)seq * LSEQ + t0) * DI + d;
  __syncthreads();
  if (fast) {
    float Rp = 1.f;
    for (int t = 0; t < TC; ++t) {
      const float* dr = &dsh[t * 48];
      float dtp = bd;
#pragma unroll
      for (int k = 0; k < 16; ++k) dtp = fmaf(dr[k], wdt[k], dtp);
      const float dtv = softplus_f(dtp);
      const float u = dtv * xsrc[(size_t)t * DI];
      const float r = __expf(-dtv);
      float a[16];
      pow_ladder(r, a);
      Rp *= r;
#pragma unroll
      for (int s = 0; s < NSTATE; ++s) st[s] = fmaf(a[s], st[s], u * dr[16 + s]);
    }
    pow_ladder(Rp, P);
  } else {
    for (int t = 0; t < TC; ++t) {
      const float* dr = &dsh[t * 48];
      float dtp = bd;
#pragma unroll
      for (int k = 0; k < 16; ++k) dtp = fmaf(dr[k], wdt[k], dtp);
      const float dtv = softplus_f(dtp);
      const float u = dtv * xsrc[(size_t)t * DI];
#pragma unroll
      for (int s = 0; s < NSTATE; ++s) {
        const float a = __expf(dtv * Aa[s]);
        st[s] = fmaf(a, st[s], u * dr[16 + s]);
        P[s] *= a;
      }
    }
  }
  float* ap = aprod  + (((size_t)seq * NCH + ch) * DI + d) * NSTATE;
  float* pp = pstate + (((size_t)seq * NCH + ch) * DI + d) * NSTATE;
#pragma unroll
  for (int s = 0; s < NSTATE; s += 4) {
    *(float4*)&ap[s] = make_float4(P[s], P[s + 1], P[s + 2], P[s + 3]);
    *(float4*)&pp[s] = make_float4(st[s], st[s + 1], st[s + 2], st[s + 3]);
  }
}

// ---------------------------------------------------------------------------
// Kernel 5 (scan pass 2): cross-chunk scan; pstate becomes hinit in-place.
// ---------------------------------------------------------------------------
__global__ __launch_bounds__(256) void k_scan2(const float* __restrict__ aprod,
                                               float* __restrict__ pstate) {
  const int flat = blockIdx.x * 256 + threadIdx.x;
  const int seq = flat >> 13;
  const int rem = flat & 8191;
  const size_t stride = (size_t)DI * NSTATE;
  const size_t base = (size_t)seq * NCH * stride + rem;
  float h = 0.f;
  for (int ch = 0; ch < NCH; ++ch) {
    const size_t o = base + (size_t)ch * stride;
    const float a = aprod[o];
    const float bsum = pstate[o];
    pstate[o] = h;
    h = fmaf(a, h, bsum);
  }
}

// ---------------------------------------------------------------------------
// Kernel 6 (scan pass 3): same fast path; y over xs in place; gate stride 512.
// ---------------------------------------------------------------------------
__global__ __launch_bounds__(256) void k_scan3(const float* __restrict__ gate,
                                               float* __restrict__ xs,
                                               const float* __restrict__ dbl,
                                               const float* __restrict__ Wdt,
                                               const float* __restrict__ bdt,
                                               const float* __restrict__ Alog,
                                               const float* __restrict__ Dv,
                                               const float* __restrict__ hinit) {
  __shared__ float dsh[TC * 48];
  const int ch = blockIdx.x, seq = blockIdx.y;
  const int tid = threadIdx.x;
  const int d = (blockIdx.z << 8) + tid;
  const int t0 = ch * TC;
  const float* dsrc = dbl + ((size_t)seq * LSEQ + t0) * 48;
#pragma unroll
  for (int i = 0; i < 6; ++i) dsh[tid + (i << 8)] = dsrc[tid + (i << 8)];
  float wdt[16], Aa[16], st[16];
#pragma unroll
  for (int k = 0; k < 16; ++k) wdt[k] = Wdt[(size_t)k * DI + d];
  const float bd = bdt[d];
  const float Dp = Dv[d];
  const float* hp = hinit + (((size_t)seq * NCH + ch) * DI + d) * NSTATE;
  bool fast = true;
#pragma unroll
  for (int s = 0; s < NSTATE; ++s) {
    const float Av = __expf(Alog[d * NSTATE + s]);
    Aa[s] = -Av;
    fast = fast && (fabsf(Av - (float)(s + 1)) < 1e-3f);
    st[s] = hp[s];
  }
  float* xrow = xs + ((size_t)seq * LSEQ + t0) * DI + d;
  const float* grow = gate + ((size_t)seq * LSEQ + t0) * DI + d;
  __syncthreads();
  if (fast) {
    for (int t = 0; t < TC; ++t) {
      const float* dr = &dsh[t * 48];
      float dtp = bd;
#pragma unroll
      for (int k = 0; k < 16; ++k) dtp = fmaf(dr[k], wdt[k], dtp);
      const float dtv = softplus_f(dtp);
      const float xsv = xrow[(size_t)t * DI];
      const float u = dtv * xsv;
      const float r = __expf(-dtv);
      float a[16];
      pow_ladder(r, a);
      float y = 0.f;
#pragma unroll
      for (int s = 0; s < NSTATE; ++s) {
        st[s] = fmaf(a[s], st[s], u * dr[16 + s]);
        y = fmaf(st[s], dr[32 + s], y);
      }
      y = fmaf(xsv, Dp, y);
      y *= silu_f(grow[(size_t)t * DI]);
      xrow[(size_t)t * DI] = y;
    }
  } else {
    for (int t = 0; t < TC; ++t) {
      const float* dr = &dsh[t * 48];
      float dtp = bd;
#pragma unroll
      for (int k = 0; k < 16; ++k) dtp = fmaf(dr[k], wdt[k], dtp);
      const float dtv = softplus_f(dtp);
      const float xsv = xrow[(size_t)t * DI];
      const float u = dtv * xsv;
      float y = 0.f;
#pragma unroll
      for (int s = 0; s < NSTATE; ++s) {
        const float a = __expf(dtv * Aa[s]);
        st[s] = fmaf(a, st[s], u * dr[16 + s]);
        y = fmaf(st[s], dr[32 + s], y);
      }
      y = fmaf(xsv, Dp, y);
      y *= silu_f(grow[(size_t)t * DI]);
      xrow[(size_t)t * DI] = y;
    }
  }
}

// ---------------------------------------------------------------------------
// Kernel 8 (fused combine + out-proj): A row = avg of 4 unflipped y rows,
// computed while staging into LDS. out[b][c][t] = A[t][:] @ W_out[:][c].
// ---------------------------------------------------------------------------
__global__ __launch_bounds__(256) void k_gemm_out(const float* __restrict__ y,
                                                  const float* __restrict__ Wout,
                                                  float* __restrict__ out) {
  __shared__ float smem[64 * 64 + 64 * 128];
  float* Ash = smem;
  float* Bsh = smem + 64 * 64;
  const int bt = blockIdx.x;
  const int b = bt >> 6, tt = bt & 63;
  const int t0 = tt << 6;
  const int c0 = blockIdx.y << 7;
  const int tid = threadIdx.x;
  const int rq = tid >> 4, k4 = tid & 15;
  const int cq = tid & 31, dr8 = tid >> 5;
  const int tx = tid & 31, ty = tid >> 5;
  const int hf = (63 - tt) << 6;   // flipped h base
  float acc[8][4];
#pragma unroll
  for (int i = 0; i < 8; ++i)
#pragma unroll
    for (int j = 0; j < 4; ++j) acc[i][j] = 0.f;

  for (int kc = 0; kc < 512; kc += 64) {
#pragma unroll
    for (int i = 0; i < 4; ++i) {
      const int row = rq + (i << 4);
      const int wf = 63 - row;
      const size_t off = kc + (k4 << 2);
      const float4 v0 = *(const float4*)&y[(((size_t)(0 + b) * LSEQ) + t0 + row) * DI + off];
      const float4 v1 = *(const float4*)&y[(((size_t)(2 + b) * LSEQ) + t0 + wf)  * DI + off];
      const float4 v2 = *(const float4*)&y[(((size_t)(4 + b) * LSEQ) + hf + row) * DI + off];
      const float4 v3 = *(const float4*)&y[(((size_t)(6 + b) * LSEQ) + hf + wf)  * DI + off];
      float4 av;
      av.x = 0.25f * (v0.x + v1.x + v2.x + v3.x);
      av.y = 0.25f * (v0.y + v1.y + v2.y + v3.y);
      av.z = 0.25f * (v0.z + v1.z + v2.z + v3.z);
      av.w = 0.25f * (v0.w + v1.w + v2.w + v3.w);
      *(float4*)&Ash[row * 64 + (k4 << 2)] = av;
    }
#pragma unroll
    for (int i = 0; i < 8; ++i) {
      const int kk = dr8 + (i << 3);
      *(float4*)&Bsh[kk * 128 + cq * 4] =
          *(const float4*)&Wout[(size_t)(kc + kk) * 256 + c0 + cq * 4];
    }
    __syncthreads();
#pragma unroll
    for (int kk = 0; kk < 64; ++kk) {
      const float4 bv = *(const float4*)&Bsh[kk * 128 + tx * 4];
      const float br[4] = {bv.x, bv.y, bv.z, bv.w};
#pragma unroll
      for (int i = 0; i < 8; ++i) {
        const float av = Ash[(ty * 8 + i) * 64 + kk];
#pragma unroll
        for (int j = 0; j < 4; ++j) acc[i][j] = fmaf(av, br[j], acc[i][j]);
      }
    }
    __syncthreads();
  }
  float* Clds = smem;
  __syncthreads();
#pragma unroll
  for (int i = 0; i < 8; ++i)
#pragma unroll
    for (int j = 0; j < 4; ++j) Clds[(tx * 4 + j) * 65 + ty * 8 + i] = acc[i][j];
  __syncthreads();
#pragma unroll
  for (int rr = 0; rr < 32; ++rr) {
    const int idx = rr * 256 + tid;
    const int cl = idx >> 6, tl = idx & 63;
    out[((size_t)b * 256 + c0 + cl) * LSEQ + t0 + tl] = Clds[cl * 65 + tl];
  }
}

// ---------------------------------------------------------------------------
extern "C" void kernel_launch(void* const* d_in, const int* in_sizes, int n_in,
                              void* d_out, int out_size, void* d_ws, size_t ws_size,
                              hipStream_t stream) {
  const float* x     = (const float*)d_in[0];
  const float* W_in  = (const float*)d_in[1];
  const float* convw = (const float*)d_in[2];
  const float* convb = (const float*)d_in[3];
  const float* W_x   = (const float*)d_in[4];
  const float* W_dt  = (const float*)d_in[5];
  const float* b_dt  = (const float*)d_in[6];
  const float* A_log = (const float*)d_in[7];
  const float* Dvec  = (const float*)d_in[8];
  const float* W_out = (const float*)d_in[9];
  float* out = (float*)d_out;

  float* ws   = (float*)d_ws;
  float* xm   = ws + XM_OFF;
  float* gate = ws + GATE_OFF;
  float* xs   = ws + XS_OFF;
  float* dbl  = ws + DBL_OFF;
  float* ap   = ws + AP_OFF;   // aliases xm (dead after conv)
  float* ps   = ws + PS_OFF;   // aliases xm upper half

  // bf16-split buffers (dead after gemm_in)
  u16* xTh   = (u16*)(ws + SPLIT_OFF);   // [2][4096][256] bf16
  u16* xTl   = xTh + 2097152;
  u16* WinTh = xTl + 2097152;            // [1024][256] bf16
  u16* WinTl = WinTh + 262144;

  k_split<<<dim3(64, 4, 2), 256, 0, stream>>>(x, xTh, xTl, 256, 4096);
  k_split<<<dim3(16, 4, 1), 256, 0, stream>>>(W_in, WinTh, WinTl, 256, 1024);
  k_gemm_in_mfma<<<dim3(256, 8), 256, 0, stream>>>(xTh, xTl, WinTh, WinTl, xm, gate);
  k_conv<<<dim3(256, 8, 2), 256, 0, stream>>>(xm, convw, convb, xs);
  k_gemm_x<<<dim3(2048), 256, 0, stream>>>(xs, W_x, dbl);
  k_scan1<<<dim3(NCH, 8, 2), 256, 0, stream>>>(xs, dbl, W_dt, b_dt, A_log, ap, ps);
  k_scan2<<<dim3(256), 256, 0, stream>>>(ap, ps);
  k_scan3<<<dim3(NCH, 8, 2), 256, 0, stream>>>(gate, xs, dbl, W_dt, b_dt, A_log, Dvec, ps);
  k_gemm_out<<<dim3(128, 2), 256, 0, stream>>>(xs, W_out, out);
}

// Round 9
// 412.531 us; speedup vs baseline: 1.5498x; 1.0620x over previous
//
#include <hip/hip_runtime.h>
#include <cstdint>
#include <cstddef>

// Sizes
#define LSEQ 4096
#define DI   512
#define NSTATE 16
#define TC 32     // scan chunk length
#define NCH 128   // number of chunks (LSEQ/TC)

// Workspace layout (floats), total 54,263,808 fl = 217 MB:
//  xm   : [8][4096][512] @ 0          (dead after conv -> reused by ap/ps)
//  gate : [8][4096][512] @ 16,777,216
//  xs   : [8][4096][512] @ 33,554,432 (becomes y in-place after scan3)
//  dbl  : [8][4096][48]  @ 50,331,648
//  split: bf16 bufs      @ 51,904,512 (dead after gemm_in)
//  ap   : [8][128][512][16] @ 0          (aliases xm)
//  ps   : [8][128][512][16] @ 8,388,608  (aliases xm upper half)
#define XM_OFF    0
#define GATE_OFF  16777216
#define XS_OFF    33554432
#define DBL_OFF   50331648
#define SPLIT_OFF 51904512
#define AP_OFF    0
#define PS_OFF    8388608

typedef unsigned short u16;
typedef __attribute__((ext_vector_type(8))) short s8v;    // 8 bf16 (4 VGPR)
typedef __attribute__((ext_vector_type(4))) float f4v;    // 4 fp32 acc
typedef __attribute__((ext_vector_type(4))) unsigned int u32x4;

#ifndef __has_builtin
#define __has_builtin(x) 0
#endif
#if __has_builtin(__builtin_amdgcn_global_load_lds)
#define USE_GLL 1
#else
#define USE_GLL 0
#endif

__device__ __forceinline__ float silu_f(float v) {
  return v * __frcp_rn(1.f + __expf(-v));
}
__device__ __forceinline__ float softplus_f(float v) {
  // max(v,0) + log(1+exp(-|v|)); arg in (1,2], v_log-based, abs err ~1e-6
  return fmaxf(v, 0.f) + __logf(1.f + __expf(-fabsf(v)));
}
__device__ __forceinline__ u16 bf16_hi(float v) {   // RNE truncate to bf16
  unsigned u = __float_as_uint(v);
  return (u16)((u + 0x7fffu + ((u >> 16) & 1u)) >> 16);
}
__device__ __forceinline__ float bf16_f(u16 h) { return __uint_as_float(((unsigned)h) << 16); }

__device__ __forceinline__ void gld16(const u16* g, u16* l, int lane) {
#if USE_GLL
  __builtin_amdgcn_global_load_lds((const __attribute__((address_space(1))) void*)g,
                                   (__attribute__((address_space(3))) void*)l, 16, 0, 0);
#else
  *(u32x4*)(l + lane * 8) = *(const u32x4*)g;
#endif
}

// powers r^1..r^16 via log-depth ladder (15 muls, depth ~4)
__device__ __forceinline__ void pow_ladder(float r, float* a) {
  const float r2 = r * r, r4 = r2 * r2, r8 = r4 * r4;
  a[0] = r;        a[1] = r2;       a[2] = r2 * r;   a[3] = r4;
  a[4] = r4 * r;   a[5] = r4 * r2;  a[6] = r4 * a[2]; a[7] = r8;
  a[8] = r8 * r;   a[9] = r8 * r2;  a[10] = r8 * a[2]; a[11] = r8 * r4;
  a[12] = r8 * a[4]; a[13] = r8 * a[5]; a[14] = r8 * a[6]; a[15] = r8 * r8;
}

// ---------------------------------------------------------------------------
// k_split: transpose fp32 [R][C] (batched) -> bf16 hi/lo [C][R]
// ---------------------------------------------------------------------------
__global__ __launch_bounds__(256) void k_split(const float* __restrict__ in,
                                               u16* __restrict__ oh,
                                               u16* __restrict__ ol,
                                               int R, int C) {
  __shared__ float tile[64][65];
  const size_t zoff = (size_t)blockIdx.z * R * C;
  in += zoff; oh += zoff; ol += zoff;
  const int c0 = blockIdx.x << 6, r0 = blockIdx.y << 6;
  const int tid = threadIdx.x;
  const int tx = tid & 63, ty = tid >> 6;
#pragma unroll
  for (int i = 0; i < 16; ++i) {
    const int r = ty + (i << 2);
    tile[r][tx] = in[(size_t)(r0 + r) * C + c0 + tx];
  }
  __syncthreads();
#pragma unroll
  for (int i = 0; i < 16; ++i) {
    const int cc = ty + (i << 2);
    const float v = tile[tx][cc];              // = in[r0+tx][c0+cc]
    const u16 h = bf16_hi(v);
    const size_t o = (size_t)(c0 + cc) * R + r0 + tx;
    oh[o] = h;
    ol[o] = bf16_hi(v - bf16_f(h));
  }
}

// ---------------------------------------------------------------------------
// Kernel 1: [xm|gate] = z @ W_in via bf16x2-split MFMA, 128x128 tile, BK=32.
// ---------------------------------------------------------------------------
__global__ __launch_bounds__(256) void k_gemm_in_mfma(const u16* __restrict__ xTh,
                                                      const u16* __restrict__ xTl,
                                                      const u16* __restrict__ Wh,
                                                      const u16* __restrict__ Wl,
                                                      float* __restrict__ xm,
                                                      float* __restrict__ gate) {
  __shared__ __attribute__((aligned(16))) u16 lds[4 * 128 * 32];  // Ah,Al,Bh,Bl
  u16* Ah = lds;
  u16* Al = lds + 4096;
  u16* Bh = lds + 8192;
  u16* Bl = lds + 12288;
  const int rt = blockIdx.x;            // 256 row tiles (128 rows each)
  const int nt = blockIdx.y;            // 8 col tiles (128 cols each)
  const int seq = rt >> 5, hl2 = rt & 31;
  const int b = seq & 1, dir = seq >> 1;
  const int tid = threadIdx.x;
  const int lane = tid & 63, wid = tid >> 6;
  const int wr = wid >> 1, wc = wid & 1;

  const u16* gsrc = (wid == 0) ? xTh : (wid == 1) ? xTl : (wid == 2) ? Wh : Wl;
  u16* ldst = lds + (wid << 12);
  size_t roff[8];
#pragma unroll
  for (int i = 0; i < 8; ++i) {
    const int r = (i << 4) + (lane >> 2);
    size_t off;
    if (wid < 2) {
      const int hl = (hl2 << 1) + (r >> 6), w = r & 63;
      const int hp = (dir & 2) ? 63 - hl : hl;
      const int wp = (dir & 1) ? 63 - w : w;
      off = ((size_t)((b << 12) + (hp << 6) + wp)) << 8;
    } else {
      off = ((size_t)((nt << 7) + r)) << 8;
    }
    roff[i] = off + ((lane & 3) << 3);
  }

  f4v acc[4][4];
  const f4v z4 = {0.f, 0.f, 0.f, 0.f};
#pragma unroll
  for (int m = 0; m < 4; ++m)
#pragma unroll
    for (int n = 0; n < 4; ++n) acc[m][n] = z4;

  const int fr = lane & 15;
  const int kg = (lane >> 4) << 3;

  for (int kc = 0; kc < 256; kc += 32) {
    __syncthreads();
#pragma unroll
    for (int i = 0; i < 8; ++i) gld16(gsrc + roff[i] + kc, ldst + (i << 9), lane);
    __syncthreads();
    s8v Afh[4], Afl[4], Bfh[4], Bfl[4];
#pragma unroll
    for (int m = 0; m < 4; ++m) {
      const int row = (wr << 6) + (m << 4) + fr;
      Afh[m] = *(const s8v*)&Ah[row * 32 + kg];
      Afl[m] = *(const s8v*)&Al[row * 32 + kg];
    }
#pragma unroll
    for (int n = 0; n < 4; ++n) {
      const int row = (wc << 6) + (n << 4) + fr;
      Bfh[n] = *(const s8v*)&Bh[row * 32 + kg];
      Bfl[n] = *(const s8v*)&Bl[row * 32 + kg];
    }
#pragma unroll
    for (int m = 0; m < 4; ++m)
#pragma unroll
      for (int n = 0; n < 4; ++n) {
        acc[m][n] = __builtin_amdgcn_mfma_f32_16x16x32_bf16(Afh[m], Bfh[n], acc[m][n], 0, 0, 0);
        acc[m][n] = __builtin_amdgcn_mfma_f32_16x16x32_bf16(Afh[m], Bfl[n], acc[m][n], 0, 0, 0);
        acc[m][n] = __builtin_amdgcn_mfma_f32_16x16x32_bf16(Afl[m], Bfh[n], acc[m][n], 0, 0, 0);
      }
  }
  const int rg = (lane >> 4) << 2;
  float* obuf = (nt & 4) ? gate : xm;
  const int ncol = (nt & 3) << 7;
  float* obase = obuf + ((size_t)((rt << 7) + (wr << 6) + rg)) * DI + ncol + (wc << 6) + fr;
#pragma unroll
  for (int m = 0; m < 4; ++m)
#pragma unroll
    for (int n = 0; n < 4; ++n)
#pragma unroll
      for (int j = 0; j < 4; ++j)
        obase[(size_t)((m << 4) + j) * DI + (n << 4)] = acc[m][n][j];
}

// ---------------------------------------------------------------------------
// Kernel 2: depthwise causal conv(4) + bias + silu : xm -> xs (stride 512)
// ---------------------------------------------------------------------------
__global__ __launch_bounds__(256) void k_conv(const float* __restrict__ xmb,
                                              const float* __restrict__ cw,
                                              const float* __restrict__ cb,
                                              float* __restrict__ xs) {
  const int t0  = blockIdx.x << 4;
  const int seq = blockIdx.y;
  const int d   = (blockIdx.z << 8) + threadIdx.x;
  const float* xm = xmb + (size_t)seq * LSEQ * DI + d;
  const float w0 = cw[d * 4], w1 = cw[d * 4 + 1], w2 = cw[d * 4 + 2], w3 = cw[d * 4 + 3];
  const float bias = cb[d];
  float r0 = (t0 >= 3) ? xm[(size_t)(t0 - 3) * DI] : 0.f;
  float r1 = (t0 >= 2) ? xm[(size_t)(t0 - 2) * DI] : 0.f;
  float r2 = (t0 >= 1) ? xm[(size_t)(t0 - 1) * DI] : 0.f;
  float* orow = xs + ((size_t)seq * LSEQ + t0) * DI + d;
#pragma unroll
  for (int i = 0; i < 16; ++i) {
    const float r3 = xm[(size_t)(t0 + i) * DI];
    const float v = fmaf(w0, r0, fmaf(w1, r1, fmaf(w2, r2, fmaf(w3, r3, bias))));
    orow[(size_t)i * DI] = silu_f(v);
    r0 = r1; r1 = r2; r2 = r3;
  }
}

// ---------------------------------------------------------------------------
// Kernel 3: dbl[row][0:48] = xs[row][:] @ W_x   (16 rows per block)
// ---------------------------------------------------------------------------
__global__ __launch_bounds__(256) void k_gemm_x(const float* __restrict__ xs,
                                                const float* __restrict__ Wx,
                                                float* __restrict__ dbl) {
  __shared__ float xsh[16][512];
  const int rb  = blockIdx.x;
  const int tid = threadIdx.x;
  const int r = tid >> 4, k4 = tid & 15;
  const float* src = xs + (size_t)rb * 16 * DI;
#pragma unroll
  for (int i = 0; i < 8; ++i) {
    const int k = (i << 6) + (k4 << 2);
    *(float4*)&xsh[r][k] = *(const float4*)&src[(size_t)r * DI + k];
  }
  __syncthreads();
  if (tid < 192) {
    const int col = tid % 48;
    const int rg  = tid / 48;
    float a0 = 0.f, a1 = 0.f, a2 = 0.f, a3 = 0.f;
    for (int k = 0; k < 512; k += 4) {
      float wv0 = Wx[(size_t)(k + 0) * 48 + col];
      float wv1 = Wx[(size_t)(k + 1) * 48 + col];
      float wv2 = Wx[(size_t)(k + 2) * 48 + col];
      float wv3 = Wx[(size_t)(k + 3) * 48 + col];
      const float4 x0 = *(const float4*)&xsh[rg * 4 + 0][k];
      const float4 x1 = *(const float4*)&xsh[rg * 4 + 1][k];
      const float4 x2 = *(const float4*)&xsh[rg * 4 + 2][k];
      const float4 x3 = *(const float4*)&xsh[rg * 4 + 3][k];
      a0 = fmaf(x0.x, wv0, fmaf(x0.y, wv1, fmaf(x0.z, wv2, fmaf(x0.w, wv3, a0))));
      a1 = fmaf(x1.x, wv0, fmaf(x1.y, wv1, fmaf(x1.z, wv2, fmaf(x1.w, wv3, a1))));
      a2 = fmaf(x2.x, wv0, fmaf(x2.y, wv1, fmaf(x2.z, wv2, fmaf(x2.w, wv3, a2))));
      a3 = fmaf(x3.x, wv0, fmaf(x3.y, wv1, fmaf(x3.z, wv2, fmaf(x3.w, wv3, a3))));
    }
    const size_t base = ((size_t)rb * 16 + rg * 4) * 48 + col;
    dbl[base] = a0; dbl[base + 48] = a1; dbl[base + 96] = a2; dbl[base + 144] = a3;
  }
}

// ---------------------------------------------------------------------------
// Kernel 4 (scan pass 1)
// ---------------------------------------------------------------------------
__global__ __launch_bounds__(256) void k_scan1(const float* __restrict__ xs,
                                               const float* __restrict__ dbl,
                                               const float* __restrict__ Wdt,
                                               const float* __restrict__ bdt,
                                               const float* __restrict__ Alog,
                                               float* __restrict__ aprod,
                                               float* __restrict__ pstate) {
  __shared__ float dsh[TC * 48];
  const int ch = blockIdx.x, seq = blockIdx.y;
  const int tid = threadIdx.x;
  const int d = (blockIdx.z << 8) + tid;
  const int t0 = ch * TC;
  const float* dsrc = dbl + ((size_t)seq * LSEQ + t0) * 48;
#pragma unroll
  for (int i = 0; i < 6; ++i) dsh[tid + (i << 8)] = dsrc[tid + (i << 8)];
  float wdt[16], Aa[16], st[16], P[16];
#pragma unroll
  for (int k = 0; k < 16; ++k) wdt[k] = Wdt[(size_t)k * DI + d];
  const float bd = bdt[d];
  bool fast = true;
#pragma unroll
  for (int s = 0; s < NSTATE; ++s) {
    const float Av = __expf(Alog[d * NSTATE + s]);
    Aa[s] = -Av;
    fast = fast && (fabsf(Av - (float)(s + 1)) < 1e-3f);
    st[s] = 0.f; P[s] = 1.f;
  }
  const float* xsrc = xs + ((size_t)seq * LSEQ + t0) * DI + d;
  __syncthreads();
  if (fast) {
    float Rp = 1.f;
    for (int t = 0; t < TC; ++t) {
      const float* dr = &dsh[t * 48];
      float dtp = bd;
#pragma unroll
      for (int k = 0; k < 16; ++k) dtp = fmaf(dr[k], wdt[k], dtp);
      const float dtv = softplus_f(dtp);
      const float u = dtv * xsrc[(size_t)t * DI];
      const float r = __expf(-dtv);
      float a[16];
      pow_ladder(r, a);
      Rp *= r;
#pragma unroll
      for (int s = 0; s < NSTATE; ++s) st[s] = fmaf(a[s], st[s], u * dr[16 + s]);
    }
    pow_ladder(Rp, P);
  } else {
    for (int t = 0; t < TC; ++t) {
      const float* dr = &dsh[t * 48];
      float dtp = bd;
#pragma unroll
      for (int k = 0; k < 16; ++k) dtp = fmaf(dr[k], wdt[k], dtp);
      const float dtv = softplus_f(dtp);
      const float u = dtv * xsrc[(size_t)t * DI];
#pragma unroll
      for (int s = 0; s < NSTATE; ++s) {
        const float a = __expf(dtv * Aa[s]);
        st[s] = fmaf(a, st[s], u * dr[16 + s]);
        P[s] *= a;
      }
    }
  }
  float* ap = aprod  + (((size_t)seq * NCH + ch) * DI + d) * NSTATE;
  float* pp = pstate + (((size_t)seq * NCH + ch) * DI + d) * NSTATE;
#pragma unroll
  for (int s = 0; s < NSTATE; s += 4) {
    *(float4*)&ap[s] = make_float4(P[s], P[s + 1], P[s + 2], P[s + 3]);
    *(float4*)&pp[s] = make_float4(st[s], st[s + 1], st[s + 2], st[s + 3]);
  }
}

// ---------------------------------------------------------------------------
// Kernel 5 (scan pass 2): cross-chunk scan; pstate becomes hinit in-place.
// ---------------------------------------------------------------------------
__global__ __launch_bounds__(256) void k_scan2(const float* __restrict__ aprod,
                                               float* __restrict__ pstate) {
  const int flat = blockIdx.x * 256 + threadIdx.x;
  const int seq = flat >> 13;
  const int rem = flat & 8191;
  const size_t stride = (size_t)DI * NSTATE;
  const size_t base = (size_t)seq * NCH * stride + rem;
  float h = 0.f;
  for (int ch = 0; ch < NCH; ++ch) {
    const size_t o = base + (size_t)ch * stride;
    const float a = aprod[o];
    const float bsum = pstate[o];
    pstate[o] = h;
    h = fmaf(a, h, bsum);
  }
}

// ---------------------------------------------------------------------------
// Kernel 6 (scan pass 3): same fast path; y over xs in place; gate stride 512.
// ---------------------------------------------------------------------------
__global__ __launch_bounds__(256) void k_scan3(const float* __restrict__ gate,
                                               float* __restrict__ xs,
                                               const float* __restrict__ dbl,
                                               const float* __restrict__ Wdt,
                                               const float* __restrict__ bdt,
                                               const float* __restrict__ Alog,
                                               const float* __restrict__ Dv,
                                               const float* __restrict__ hinit) {
  __shared__ float dsh[TC * 48];
  const int ch = blockIdx.x, seq = blockIdx.y;
  const int tid = threadIdx.x;
  const int d = (blockIdx.z << 8) + tid;
  const int t0 = ch * TC;
  const float* dsrc = dbl + ((size_t)seq * LSEQ + t0) * 48;
#pragma unroll
  for (int i = 0; i < 6; ++i) dsh[tid + (i << 8)] = dsrc[tid + (i << 8)];
  float wdt[16], Aa[16], st[16];
#pragma unroll
  for (int k = 0; k < 16; ++k) wdt[k] = Wdt[(size_t)k * DI + d];
  const float bd = bdt[d];
  const float Dp = Dv[d];
  const float* hp = hinit + (((size_t)seq * NCH + ch) * DI + d) * NSTATE;
  bool fast = true;
#pragma unroll
  for (int s = 0; s < NSTATE; ++s) {
    const float Av = __expf(Alog[d * NSTATE + s]);
    Aa[s] = -Av;
    fast = fast && (fabsf(Av - (float)(s + 1)) < 1e-3f);
    st[s] = hp[s];
  }
  float* xrow = xs + ((size_t)seq * LSEQ + t0) * DI + d;
  const float* grow = gate + ((size_t)seq * LSEQ + t0) * DI + d;
  __syncthreads();
  if (fast) {
    for (int t = 0; t < TC; ++t) {
      const float* dr = &dsh[t * 48];
      float dtp = bd;
#pragma unroll
      for (int k = 0; k < 16; ++k) dtp = fmaf(dr[k], wdt[k], dtp);
      const float dtv = softplus_f(dtp);
      const float xsv = xrow[(size_t)t * DI];
      const float u = dtv * xsv;
      const float r = __expf(-dtv);
      float a[16];
      pow_ladder(r, a);
      float y = 0.f;
#pragma unroll
      for (int s = 0; s < NSTATE; ++s) {
        st[s] = fmaf(a[s], st[s], u * dr[16 + s]);
        y = fmaf(st[s], dr[32 + s], y);
      }
      y = fmaf(xsv, Dp, y);
      y *= silu_f(grow[(size_t)t * DI]);
      xrow[(size_t)t * DI] = y;
    }
  } else {
    for (int t = 0; t < TC; ++t) {
      const float* dr = &dsh[t * 48];
      float dtp = bd;
#pragma unroll
      for (int k = 0; k < 16; ++k) dtp = fmaf(dr[k], wdt[k], dtp);
      const float dtv = softplus_f(dtp);
      const float xsv = xrow[(size_t)t * DI];
      const float u = dtv * xsv;
      float y = 0.f;
#pragma unroll
      for (int s = 0; s < NSTATE; ++s) {
        const float a = __expf(dtv * Aa[s]);
        st[s] = fmaf(a, st[s], u * dr[16 + s]);
        y = fmaf(st[s], dr[32 + s], y);
      }
      y = fmaf(xsv, Dp, y);
      y *= silu_f(grow[(size_t)t * DI]);
      xrow[(size_t)t * DI] = y;
    }
  }
}

// ---------------------------------------------------------------------------
// Kernel 8 (fused combine + out-proj), v2: 32 t-rows x 128 c-cols per block,
// grid 512. A staged k-major [64][33] (conflict-free column reads), B [64][132]
// (broadcast float4 reads), C stored direct from registers (coalesced, no LDS
// transpose). A rows are the 0.25*(4-flip) average, h constant per block.
// ---------------------------------------------------------------------------
__global__ __launch_bounds__(256, 2) void k_gemm_out(const float* __restrict__ y,
                                                     const float* __restrict__ Wout,
                                                     float* __restrict__ out) {
  __shared__ float Ash[64 * 33];
  __shared__ float Bsh[64 * 132];
  const int bx = blockIdx.x;                 // 0..255 : b*128 + tt
  const int b = bx >> 7, tt = bx & 127;
  const int t0 = tt << 5;                    // 32 rows
  const int c0 = blockIdx.y << 7;            // 128 cols
  const int tid = threadIdx.x;
  const int h = t0 >> 6, hf = 63 - h;        // constant per block
  const int w0 = t0 & 63;
  // A-stage mapping
  const int ar = tid >> 3, ak = tid & 7;
  const int w = w0 + ar, wf = 63 - w;
  const size_t row0 = ((size_t)(0 + b) * LSEQ + (h << 6) + w) * DI;
  const size_t row1 = ((size_t)(2 + b) * LSEQ + (h << 6) + wf) * DI;
  const size_t row2 = ((size_t)(4 + b) * LSEQ + (hf << 6) + w) * DI;
  const size_t row3 = ((size_t)(6 + b) * LSEQ + (hf << 6) + wf) * DI;
  // B-stage mapping
  const int bk = tid >> 3, bc = tid & 7;
  // compute mapping
  const int tx = tid & 31, cy = tid >> 5;    // 8 c-groups of 16 cols
  float acc[16];
#pragma unroll
  for (int j = 0; j < 16; ++j) acc[j] = 0.f;

  for (int kc = 0; kc < 512; kc += 64) {
#pragma unroll
    for (int f = 0; f < 2; ++f) {
      const int kl = (ak << 3) + (f << 2);
      const int k = kl + kc;
      const float4 v0 = *(const float4*)&y[row0 + k];
      const float4 v1 = *(const float4*)&y[row1 + k];
      const float4 v2 = *(const float4*)&y[row2 + k];
      const float4 v3 = *(const float4*)&y[row3 + k];
      Ash[(kl + 0) * 33 + ar] = 0.25f * (v0.x + v1.x + v2.x + v3.x);
      Ash[(kl + 1) * 33 + ar] = 0.25f * (v0.y + v1.y + v2.y + v3.y);
      Ash[(kl + 2) * 33 + ar] = 0.25f * (v0.z + v1.z + v2.z + v3.z);
      Ash[(kl + 3) * 33 + ar] = 0.25f * (v0.w + v1.w + v2.w + v3.w);
    }
#pragma unroll
    for (int rr = 0; rr < 2; ++rr) {
      const int kk = bk + (rr << 5);
#pragma unroll
      for (int i = 0; i < 4; ++i) {
        const int c = (bc << 2) + (i << 5);
        *(float4*)&Bsh[kk * 132 + c] =
            *(const float4*)&Wout[(size_t)(kc + kk) * 256 + c0 + c];
      }
    }
    __syncthreads();
#pragma unroll
    for (int kk = 0; kk < 64; ++kk) {
      const float a = Ash[kk * 33 + tx];
      const float* bp = &Bsh[kk * 132 + (cy << 4)];
      const float4 b0 = *(const float4*)&bp[0];
      const float4 b1 = *(const float4*)&bp[4];
      const float4 b2 = *(const float4*)&bp[8];
      const float4 b3 = *(const float4*)&bp[12];
      acc[0]  = fmaf(a, b0.x, acc[0]);   acc[1]  = fmaf(a, b0.y, acc[1]);
      acc[2]  = fmaf(a, b0.z, acc[2]);   acc[3]  = fmaf(a, b0.w, acc[3]);
      acc[4]  = fmaf(a, b1.x, acc[4]);   acc[5]  = fmaf(a, b1.y, acc[5]);
      acc[6]  = fmaf(a, b1.z, acc[6]);   acc[7]  = fmaf(a, b1.w, acc[7]);
      acc[8]  = fmaf(a, b2.x, acc[8]);   acc[9]  = fmaf(a, b2.y, acc[9]);
      acc[10] = fmaf(a, b2.z, acc[10]);  acc[11] = fmaf(a, b2.w, acc[11]);
      acc[12] = fmaf(a, b3.x, acc[12]);  acc[13] = fmaf(a, b3.y, acc[13]);
      acc[14] = fmaf(a, b3.z, acc[14]);  acc[15] = fmaf(a, b3.w, acc[15]);
    }
    __syncthreads();
  }
#pragma unroll
  for (int j = 0; j < 16; ++j) {
    const int c = c0 + (cy << 4) + j;
    out[((size_t)b * 256 + c) * LSEQ + t0 + tx] = acc[j];
  }
}

// ---------------------------------------------------------------------------
extern "C" void kernel_launch(void* const* d_in, const int* in_sizes, int n_in,
                              void* d_out, int out_size, void* d_ws, size_t ws_size,
                              hipStream_t stream) {
  const float* x     = (const float*)d_in[0];
  const float* W_in  = (const float*)d_in[1];
  const float* convw = (const float*)d_in[2];
  const float* convb = (const float*)d_in[3];
  const float* W_x   = (const float*)d_in[4];
  const float* W_dt  = (const float*)d_in[5];
  const float* b_dt  = (const float*)d_in[6];
  const float* A_log = (const float*)d_in[7];
  const float* Dvec  = (const float*)d_in[8];
  const float* W_out = (const float*)d_in[9];
  float* out = (float*)d_out;

  float* ws   = (float*)d_ws;
  float* xm   = ws + XM_OFF;
  float* gate = ws + GATE_OFF;
  float* xs   = ws + XS_OFF;
  float* dbl  = ws + DBL_OFF;
  float* ap   = ws + AP_OFF;   // aliases xm (dead after conv)
  float* ps   = ws + PS_OFF;   // aliases xm upper half

  // bf16-split buffers (dead after gemm_in)
  u16* xTh   = (u16*)(ws + SPLIT_OFF);   // [2][4096][256] bf16
  u16* xTl   = xTh + 2097152;
  u16* WinTh = xTl + 2097152;            // [1024][256] bf16
  u16* WinTl = WinTh + 262144;

  k_split<<<dim3(64, 4, 2), 256, 0, stream>>>(x, xTh, xTl, 256, 4096);
  k_split<<<dim3(16, 4, 1), 256, 0, stream>>>(W_in, WinTh, WinTl, 256, 1024);
  k_gemm_in_mfma<<<dim3(256, 8), 256, 0, stream>>>(xTh, xTl, WinTh, WinTl, xm, gate);
  k_conv<<<dim3(256, 8, 2), 256, 0, stream>>>(xm, convw, convb, xs);
  k_gemm_x<<<dim3(2048), 256, 0, stream>>>(xs, W_x, dbl);
  k_scan1<<<dim3(NCH, 8, 2), 256, 0, stream>>>(xs, dbl, W_dt, b_dt, A_log, ap, ps);
  k_scan2<<<dim3(256), 256, 0, stream>>>(ap, ps);
  k_scan3<<<dim3(NCH, 8, 2), 256, 0, stream>>>(gate, xs, dbl, W_dt, b_dt, A_log, Dvec, ps);
  k_gemm_out<<<dim3(256, 2), 256, 0, stream>>>(xs, W_out, out);
}

// Round 10
// 406.324 us; speedup vs baseline: 1.5735x; 1.0153x over previous
//
#include <hip/hip_runtime.h>
#include <cstdint>
#include <cstddef>

// Sizes
#define LSEQ 4096
#define DI   512
#define NSTATE 16
#define TC 32     // scan chunk length
#define NCH 128   // number of chunks (LSEQ/TC)

// Workspace layout (floats), total 54,263,808 fl = 217 MB:
//  xm   : [8][4096][512] @ 0          (dead after convx -> reused by ap/ps)
//  gate : [8][4096][512] @ 16,777,216
//  xs   : [8][4096][512] @ 33,554,432 (becomes y in-place after scan3)
//  dbl  : [8][4096][48]  @ 50,331,648
//  split: bf16 bufs      @ 51,904,512 (dead after gemm_in)
//  ap   : [8][128][512][16] @ 0          (aliases xm)
//  ps   : [8][128][512][16] @ 8,388,608  (aliases xm upper half)
#define XM_OFF    0
#define GATE_OFF  16777216
#define XS_OFF    33554432
#define DBL_OFF   50331648
#define SPLIT_OFF 51904512
#define AP_OFF    0
#define PS_OFF    8388608

typedef unsigned short u16;
typedef __attribute__((ext_vector_type(8))) short s8v;    // 8 bf16 (4 VGPR)
typedef __attribute__((ext_vector_type(4))) float f4v;    // 4 fp32 acc
typedef __attribute__((ext_vector_type(4))) unsigned int u32x4;

#ifndef __has_builtin
#define __has_builtin(x) 0
#endif
#if __has_builtin(__builtin_amdgcn_global_load_lds)
#define USE_GLL 1
#else
#define USE_GLL 0
#endif

__device__ __forceinline__ float silu_f(float v) {
  return v * __frcp_rn(1.f + __expf(-v));
}
__device__ __forceinline__ float softplus_f(float v) {
  return fmaxf(v, 0.f) + __logf(1.f + __expf(-fabsf(v)));
}
__device__ __forceinline__ u16 bf16_hi(float v) {   // RNE truncate to bf16
  unsigned u = __float_as_uint(v);
  return (u16)((u + 0x7fffu + ((u >> 16) & 1u)) >> 16);
}
__device__ __forceinline__ float bf16_f(u16 h) { return __uint_as_float(((unsigned)h) << 16); }

__device__ __forceinline__ void gld16(const u16* g, u16* l, int lane) {
#if USE_GLL
  __builtin_amdgcn_global_load_lds((const __attribute__((address_space(1))) void*)g,
                                   (__attribute__((address_space(3))) void*)l, 16, 0, 0);
#else
  *(u32x4*)(l + lane * 8) = *(const u32x4*)g;
#endif
}

// powers r^1..r^16 via log-depth ladder (15 muls, depth ~4)
__device__ __forceinline__ void pow_ladder(float r, float* a) {
  const float r2 = r * r, r4 = r2 * r2, r8 = r4 * r4;
  a[0] = r;        a[1] = r2;       a[2] = r2 * r;   a[3] = r4;
  a[4] = r4 * r;   a[5] = r4 * r2;  a[6] = r4 * a[2]; a[7] = r8;
  a[8] = r8 * r;   a[9] = r8 * r2;  a[10] = r8 * a[2]; a[11] = r8 * r4;
  a[12] = r8 * a[4]; a[13] = r8 * a[5]; a[14] = r8 * a[6]; a[15] = r8 * r8;
}

// ---------------------------------------------------------------------------
// k_split: transpose fp32 [R][C] (batched) -> bf16 hi/lo [C][R]
// ---------------------------------------------------------------------------
__global__ __launch_bounds__(256) void k_split(const float* __restrict__ in,
                                               u16* __restrict__ oh,
                                               u16* __restrict__ ol,
                                               int R, int C) {
  __shared__ float tile[64][65];
  const size_t zoff = (size_t)blockIdx.z * R * C;
  in += zoff; oh += zoff; ol += zoff;
  const int c0 = blockIdx.x << 6, r0 = blockIdx.y << 6;
  const int tid = threadIdx.x;
  const int tx = tid & 63, ty = tid >> 6;
#pragma unroll
  for (int i = 0; i < 16; ++i) {
    const int r = ty + (i << 2);
    tile[r][tx] = in[(size_t)(r0 + r) * C + c0 + tx];
  }
  __syncthreads();
#pragma unroll
  for (int i = 0; i < 16; ++i) {
    const int cc = ty + (i << 2);
    const float v = tile[tx][cc];              // = in[r0+tx][c0+cc]
    const u16 h = bf16_hi(v);
    const size_t o = (size_t)(c0 + cc) * R + r0 + tx;
    oh[o] = h;
    ol[o] = bf16_hi(v - bf16_f(h));
  }
}

// ---------------------------------------------------------------------------
// Kernel 1: [xm|gate] = z @ W_in via bf16x2-split MFMA, 128x128 tile, BK=32.
// ---------------------------------------------------------------------------
__global__ __launch_bounds__(256) void k_gemm_in_mfma(const u16* __restrict__ xTh,
                                                      const u16* __restrict__ xTl,
                                                      const u16* __restrict__ Wh,
                                                      const u16* __restrict__ Wl,
                                                      float* __restrict__ xm,
                                                      float* __restrict__ gate) {
  __shared__ __attribute__((aligned(16))) u16 lds[4 * 128 * 32];  // Ah,Al,Bh,Bl
  u16* Ah = lds;
  u16* Al = lds + 4096;
  u16* Bh = lds + 8192;
  u16* Bl = lds + 12288;
  const int rt = blockIdx.x;            // 256 row tiles (128 rows each)
  const int nt = blockIdx.y;            // 8 col tiles (128 cols each)
  const int seq = rt >> 5, hl2 = rt & 31;
  const int b = seq & 1, dir = seq >> 1;
  const int tid = threadIdx.x;
  const int lane = tid & 63, wid = tid >> 6;
  const int wr = wid >> 1, wc = wid & 1;

  const u16* gsrc = (wid == 0) ? xTh : (wid == 1) ? xTl : (wid == 2) ? Wh : Wl;
  u16* ldst = lds + (wid << 12);
  size_t roff[8];
#pragma unroll
  for (int i = 0; i < 8; ++i) {
    const int r = (i << 4) + (lane >> 2);
    size_t off;
    if (wid < 2) {
      const int hl = (hl2 << 1) + (r >> 6), w = r & 63;
      const int hp = (dir & 2) ? 63 - hl : hl;
      const int wp = (dir & 1) ? 63 - w : w;
      off = ((size_t)((b << 12) + (hp << 6) + wp)) << 8;
    } else {
      off = ((size_t)((nt << 7) + r)) << 8;
    }
    roff[i] = off + ((lane & 3) << 3);
  }

  f4v acc[4][4];
  const f4v z4 = {0.f, 0.f, 0.f, 0.f};
#pragma unroll
  for (int m = 0; m < 4; ++m)
#pragma unroll
    for (int n = 0; n < 4; ++n) acc[m][n] = z4;

  const int fr = lane & 15;
  const int kg = (lane >> 4) << 3;

  for (int kc = 0; kc < 256; kc += 32) {
    __syncthreads();
#pragma unroll
    for (int i = 0; i < 8; ++i) gld16(gsrc + roff[i] + kc, ldst + (i << 9), lane);
    __syncthreads();
    s8v Afh[4], Afl[4], Bfh[4], Bfl[4];
#pragma unroll
    for (int m = 0; m < 4; ++m) {
      const int row = (wr << 6) + (m << 4) + fr;
      Afh[m] = *(const s8v*)&Ah[row * 32 + kg];
      Afl[m] = *(const s8v*)&Al[row * 32 + kg];
    }
#pragma unroll
    for (int n = 0; n < 4; ++n) {
      const int row = (wc << 6) + (n << 4) + fr;
      Bfh[n] = *(const s8v*)&Bh[row * 32 + kg];
      Bfl[n] = *(const s8v*)&Bl[row * 32 + kg];
    }
#pragma unroll
    for (int m = 0; m < 4; ++m)
#pragma unroll
      for (int n = 0; n < 4; ++n) {
        acc[m][n] = __builtin_amdgcn_mfma_f32_16x16x32_bf16(Afh[m], Bfh[n], acc[m][n], 0, 0, 0);
        acc[m][n] = __builtin_amdgcn_mfma_f32_16x16x32_bf16(Afh[m], Bfl[n], acc[m][n], 0, 0, 0);
        acc[m][n] = __builtin_amdgcn_mfma_f32_16x16x32_bf16(Afl[m], Bfh[n], acc[m][n], 0, 0, 0);
      }
  }
  const int rg = (lane >> 4) << 2;
  float* obuf = (nt & 4) ? gate : xm;
  const int ncol = (nt & 3) << 7;
  float* obase = obuf + ((size_t)((rt << 7) + (wr << 6) + rg)) * DI + ncol + (wc << 6) + fr;
#pragma unroll
  for (int m = 0; m < 4; ++m)
#pragma unroll
    for (int n = 0; n < 4; ++n)
#pragma unroll
      for (int j = 0; j < 4; ++j)
        obase[(size_t)((m << 4) + j) * DI + (n << 4)] = acc[m][n][j];
}

// ---------------------------------------------------------------------------
// Kernel 2+3 fused (k_convx): conv(4)+bias+silu from xm -> xs (global + LDS),
// then dbl[row][0:48] = xs[row][:] @ W_x. 16 rows per block, 2048 blocks.
// Each thread runs the rolling conv window down its 2 d-columns (halo = 3 rows
// of the previous tile; zeros at t==0).
// ---------------------------------------------------------------------------
__global__ __launch_bounds__(256) void k_convx(const float* __restrict__ xmb,
                                               const float* __restrict__ cw,
                                               const float* __restrict__ cb,
                                               const float* __restrict__ Wx,
                                               float* __restrict__ xs,
                                               float* __restrict__ dbl) {
  __shared__ float xsh[16][512];
  const int rb  = blockIdx.x;
  const int tid = threadIdx.x;
  const int r0g = rb << 4;            // global row (seq*4096 + t)
  const int t0  = r0g & 4095;         // within-seq t (0 only at seq start)
#pragma unroll
  for (int half = 0; half < 2; ++half) {
    const int d = tid + (half << 8);
    const float w0 = cw[d * 4], w1 = cw[d * 4 + 1], w2 = cw[d * 4 + 2], w3 = cw[d * 4 + 3];
    const float bias = cb[d];
    float r0 = 0.f, r1 = 0.f, r2 = 0.f;
    if (t0 != 0) {
      r0 = xmb[((size_t)r0g - 3) * DI + d];
      r1 = xmb[((size_t)r0g - 2) * DI + d];
      r2 = xmb[((size_t)r0g - 1) * DI + d];
    }
    float* xsg = xs + (size_t)r0g * DI + d;
#pragma unroll
    for (int i = 0; i < 16; ++i) {
      const float r3 = xmb[(size_t)(r0g + i) * DI + d];
      const float v = fmaf(w0, r0, fmaf(w1, r1, fmaf(w2, r2, fmaf(w3, r3, bias))));
      const float sv = silu_f(v);
      xsh[i][d] = sv;
      xsg[(size_t)i * DI] = sv;
      r0 = r1; r1 = r2; r2 = r3;
    }
  }
  __syncthreads();
  if (tid < 192) {
    const int col = tid % 48;
    const int rg  = tid / 48;
    float a0 = 0.f, a1 = 0.f, a2 = 0.f, a3 = 0.f;
    for (int k = 0; k < 512; k += 4) {
      float wv0 = Wx[(size_t)(k + 0) * 48 + col];
      float wv1 = Wx[(size_t)(k + 1) * 48 + col];
      float wv2 = Wx[(size_t)(k + 2) * 48 + col];
      float wv3 = Wx[(size_t)(k + 3) * 48 + col];
      const float4 x0 = *(const float4*)&xsh[rg * 4 + 0][k];
      const float4 x1 = *(const float4*)&xsh[rg * 4 + 1][k];
      const float4 x2 = *(const float4*)&xsh[rg * 4 + 2][k];
      const float4 x3 = *(const float4*)&xsh[rg * 4 + 3][k];
      a0 = fmaf(x0.x, wv0, fmaf(x0.y, wv1, fmaf(x0.z, wv2, fmaf(x0.w, wv3, a0))));
      a1 = fmaf(x1.x, wv0, fmaf(x1.y, wv1, fmaf(x1.z, wv2, fmaf(x1.w, wv3, a1))));
      a2 = fmaf(x2.x, wv0, fmaf(x2.y, wv1, fmaf(x2.z, wv2, fmaf(x2.w, wv3, a2))));
      a3 = fmaf(x3.x, wv0, fmaf(x3.y, wv1, fmaf(x3.z, wv2, fmaf(x3.w, wv3, a3))));
    }
    const size_t base = ((size_t)rb * 16 + rg * 4) * 48 + col;
    dbl[base] = a0; dbl[base + 48] = a1; dbl[base + 96] = a2; dbl[base + 144] = a3;
  }
}

// ---------------------------------------------------------------------------
// Kernel 4 (scan pass 1): r = sigmoid(-dtp) == exp(-softplus(dtp));
// dtv = -log(r). One rcp+2 trans per t in fast path.
// ---------------------------------------------------------------------------
__global__ __launch_bounds__(256) void k_scan1(const float* __restrict__ xs,
                                               const float* __restrict__ dbl,
                                               const float* __restrict__ Wdt,
                                               const float* __restrict__ bdt,
                                               const float* __restrict__ Alog,
                                               float* __restrict__ aprod,
                                               float* __restrict__ pstate) {
  __shared__ float dsh[TC * 48];
  const int ch = blockIdx.x, seq = blockIdx.y;
  const int tid = threadIdx.x;
  const int d = (blockIdx.z << 8) + tid;
  const int t0 = ch * TC;
  const float* dsrc = dbl + ((size_t)seq * LSEQ + t0) * 48;
#pragma unroll
  for (int i = 0; i < 6; ++i) dsh[tid + (i << 8)] = dsrc[tid + (i << 8)];
  float wdt[16], Aa[16], st[16], P[16];
#pragma unroll
  for (int k = 0; k < 16; ++k) wdt[k] = Wdt[(size_t)k * DI + d];
  const float bd = bdt[d];
  bool fast = true;
#pragma unroll
  for (int s = 0; s < NSTATE; ++s) {
    const float Av = __expf(Alog[d * NSTATE + s]);
    Aa[s] = -Av;
    fast = fast && (fabsf(Av - (float)(s + 1)) < 1e-3f);
    st[s] = 0.f; P[s] = 1.f;
  }
  const float* xsrc = xs + ((size_t)seq * LSEQ + t0) * DI + d;
  __syncthreads();
  if (fast) {
    float Rp = 1.f;
    for (int t = 0; t < TC; ++t) {
      const float* dr = &dsh[t * 48];
      float dtp = bd;
#pragma unroll
      for (int k = 0; k < 16; ++k) dtp = fmaf(dr[k], wdt[k], dtp);
      const float r = __frcp_rn(1.f + __expf(fminf(dtp, 80.f)));
      const float dtv = -__logf(r);
      const float u = dtv * xsrc[(size_t)t * DI];
      float a[16];
      pow_ladder(r, a);
      Rp *= r;
#pragma unroll
      for (int s = 0; s < NSTATE; ++s) st[s] = fmaf(a[s], st[s], u * dr[16 + s]);
    }
    pow_ladder(Rp, P);
  } else {
    for (int t = 0; t < TC; ++t) {
      const float* dr = &dsh[t * 48];
      float dtp = bd;
#pragma unroll
      for (int k = 0; k < 16; ++k) dtp = fmaf(dr[k], wdt[k], dtp);
      const float dtv = softplus_f(dtp);
      const float u = dtv * xsrc[(size_t)t * DI];
#pragma unroll
      for (int s = 0; s < NSTATE; ++s) {
        const float a = __expf(dtv * Aa[s]);
        st[s] = fmaf(a, st[s], u * dr[16 + s]);
        P[s] *= a;
      }
    }
  }
  float* ap = aprod  + (((size_t)seq * NCH + ch) * DI + d) * NSTATE;
  float* pp = pstate + (((size_t)seq * NCH + ch) * DI + d) * NSTATE;
#pragma unroll
  for (int s = 0; s < NSTATE; s += 4) {
    *(float4*)&ap[s] = make_float4(P[s], P[s + 1], P[s + 2], P[s + 3]);
    *(float4*)&pp[s] = make_float4(st[s], st[s + 1], st[s + 2], st[s + 3]);
  }
}

// ---------------------------------------------------------------------------
// Kernel 5 (scan pass 2): cross-chunk scan; pstate becomes hinit in-place.
// ---------------------------------------------------------------------------
__global__ __launch_bounds__(256) void k_scan2(const float* __restrict__ aprod,
                                               float* __restrict__ pstate) {
  const int flat = blockIdx.x * 256 + threadIdx.x;
  const int seq = flat >> 13;
  const int rem = flat & 8191;
  const size_t stride = (size_t)DI * NSTATE;
  const size_t base = (size_t)seq * NCH * stride + rem;
  float h = 0.f;
  for (int ch = 0; ch < NCH; ++ch) {
    const size_t o = base + (size_t)ch * stride;
    const float a = aprod[o];
    const float bsum = pstate[o];
    pstate[o] = h;
    h = fmaf(a, h, bsum);
  }
}

// ---------------------------------------------------------------------------
// Kernel 6 (scan pass 3): same sigmoid fast path; y over xs in place.
// ---------------------------------------------------------------------------
__global__ __launch_bounds__(256) void k_scan3(const float* __restrict__ gate,
                                               float* __restrict__ xs,
                                               const float* __restrict__ dbl,
                                               const float* __restrict__ Wdt,
                                               const float* __restrict__ bdt,
                                               const float* __restrict__ Alog,
                                               const float* __restrict__ Dv,
                                               const float* __restrict__ hinit) {
  __shared__ float dsh[TC * 48];
  const int ch = blockIdx.x, seq = blockIdx.y;
  const int tid = threadIdx.x;
  const int d = (blockIdx.z << 8) + tid;
  const int t0 = ch * TC;
  const float* dsrc = dbl + ((size_t)seq * LSEQ + t0) * 48;
#pragma unroll
  for (int i = 0; i < 6; ++i) dsh[tid + (i << 8)] = dsrc[tid + (i << 8)];
  float wdt[16], Aa[16], st[16];
#pragma unroll
  for (int k = 0; k < 16; ++k) wdt[k] = Wdt[(size_t)k * DI + d];
  const float bd = bdt[d];
  const float Dp = Dv[d];
  const float* hp = hinit + (((size_t)seq * NCH + ch) * DI + d) * NSTATE;
  bool fast = true;
#pragma unroll
  for (int s = 0; s < NSTATE; ++s) {
    const float Av = __expf(Alog[d * NSTATE + s]);
    Aa[s] = -Av;
    fast = fast && (fabsf(Av - (float)(s + 1)) < 1e-3f);
    st[s] = hp[s];
  }
  float* xrow = xs + ((size_t)seq * LSEQ + t0) * DI + d;
  const float* grow = gate + ((size_t)seq * LSEQ + t0) * DI + d;
  __syncthreads();
  if (fast) {
    for (int t = 0; t < TC; ++t) {
      const float* dr = &dsh[t * 48];
      float dtp = bd;
#pragma unroll
      for (int k = 0; k < 16; ++k) dtp = fmaf(dr[k], wdt[k], dtp);
      const float r = __frcp_rn(1.f + __expf(fminf(dtp, 80.f)));
      const float dtv = -__logf(r);
      const float xsv = xrow[(size_t)t * DI];
      const float u = dtv * xsv;
      float a[16];
      pow_ladder(r, a);
      float y = 0.f;
#pragma unroll
      for (int s = 0; s < NSTATE; ++s) {
        st[s] = fmaf(a[s], st[s], u * dr[16 + s]);
        y = fmaf(st[s], dr[32 + s], y);
      }
      y = fmaf(xsv, Dp, y);
      y *= silu_f(grow[(size_t)t * DI]);
      xrow[(size_t)t * DI] = y;
    }
  } else {
    for (int t = 0; t < TC; ++t) {
      const float* dr = &dsh[t * 48];
      float dtp = bd;
#pragma unroll
      for (int k = 0; k < 16; ++k) dtp = fmaf(dr[k], wdt[k], dtp);
      const float dtv = softplus_f(dtp);
      const float xsv = xrow[(size_t)t * DI];
      const float u = dtv * xsv;
      float y = 0.f;
#pragma unroll
      for (int s = 0; s < NSTATE; ++s) {
        const float a = __expf(dtv * Aa[s]);
        st[s] = fmaf(a, st[s], u * dr[16 + s]);
        y = fmaf(st[s], dr[32 + s], y);
      }
      y = fmaf(xsv, Dp, y);
      y *= silu_f(grow[(size_t)t * DI]);
      xrow[(size_t)t * DI] = y;
    }
  }
}

// ---------------------------------------------------------------------------
// Kernel 8 (fused combine + out-proj), v2: 32 t-rows x 128 c-cols per block.
// ---------------------------------------------------------------------------
__global__ __launch_bounds__(256, 2) void k_gemm_out(const float* __restrict__ y,
                                                     const float* __restrict__ Wout,
                                                     float* __restrict__ out) {
  __shared__ float Ash[64 * 33];
  __shared__ float Bsh[64 * 132];
  const int bx = blockIdx.x;                 // 0..255 : b*128 + tt
  const int b = bx >> 7, tt = bx & 127;
  const int t0 = tt << 5;                    // 32 rows
  const int c0 = blockIdx.y << 7;            // 128 cols
  const int tid = threadIdx.x;
  const int h = t0 >> 6, hf = 63 - h;        // constant per block
  const int w0 = t0 & 63;
  const int ar = tid >> 3, ak = tid & 7;
  const int w = w0 + ar, wf = 63 - w;
  const size_t row0 = ((size_t)(0 + b) * LSEQ + (h << 6) + w) * DI;
  const size_t row1 = ((size_t)(2 + b) * LSEQ + (h << 6) + wf) * DI;
  const size_t row2 = ((size_t)(4 + b) * LSEQ + (hf << 6) + w) * DI;
  const size_t row3 = ((size_t)(6 + b) * LSEQ + (hf << 6) + wf) * DI;
  const int bk = tid >> 3, bc = tid & 7;
  const int tx = tid & 31, cy = tid >> 5;    // 8 c-groups of 16 cols
  float acc[16];
#pragma unroll
  for (int j = 0; j < 16; ++j) acc[j] = 0.f;

  for (int kc = 0; kc < 512; kc += 64) {
#pragma unroll
    for (int f = 0; f < 2; ++f) {
      const int kl = (ak << 3) + (f << 2);
      const int k = kl + kc;
      const float4 v0 = *(const float4*)&y[row0 + k];
      const float4 v1 = *(const float4*)&y[row1 + k];
      const float4 v2 = *(const float4*)&y[row2 + k];
      const float4 v3 = *(const float4*)&y[row3 + k];
      Ash[(kl + 0) * 33 + ar] = 0.25f * (v0.x + v1.x + v2.x + v3.x);
      Ash[(kl + 1) * 33 + ar] = 0.25f * (v0.y + v1.y + v2.y + v3.y);
      Ash[(kl + 2) * 33 + ar] = 0.25f * (v0.z + v1.z + v2.z + v3.z);
      Ash[(kl + 3) * 33 + ar] = 0.25f * (v0.w + v1.w + v2.w + v3.w);
    }
#pragma unroll
    for (int rr = 0; rr < 2; ++rr) {
      const int kk = bk + (rr << 5);
#pragma unroll
      for (int i = 0; i < 4; ++i) {
        const int c = (bc << 2) + (i << 5);
        *(float4*)&Bsh[kk * 132 + c] =
            *(const float4*)&Wout[(size_t)(kc + kk) * 256 + c0 + c];
      }
    }
    __syncthreads();
#pragma unroll
    for (int kk = 0; kk < 64; ++kk) {
      const float a = Ash[kk * 33 + tx];
      const float* bp = &Bsh[kk * 132 + (cy << 4)];
      const float4 b0 = *(const float4*)&bp[0];
      const float4 b1 = *(const float4*)&bp[4];
      const float4 b2 = *(const float4*)&bp[8];
      const float4 b3 = *(const float4*)&bp[12];
      acc[0]  = fmaf(a, b0.x, acc[0]);   acc[1]  = fmaf(a, b0.y, acc[1]);
      acc[2]  = fmaf(a, b0.z, acc[2]);   acc[3]  = fmaf(a, b0.w, acc[3]);
      acc[4]  = fmaf(a, b1.x, acc[4]);   acc[5]  = fmaf(a, b1.y, acc[5]);
      acc[6]  = fmaf(a, b1.z, acc[6]);   acc[7]  = fmaf(a, b1.w, acc[7]);
      acc[8]  = fmaf(a, b2.x, acc[8]);   acc[9]  = fmaf(a, b2.y, acc[9]);
      acc[10] = fmaf(a, b2.z, acc[10]);  acc[11] = fmaf(a, b2.w, acc[11]);
      acc[12] = fmaf(a, b3.x, acc[12]);  acc[13] = fmaf(a, b3.y, acc[13]);
      acc[14] = fmaf(a, b3.z, acc[14]);  acc[15] = fmaf(a, b3.w, acc[15]);
    }
    __syncthreads();
  }
#pragma unroll
  for (int j = 0; j < 16; ++j) {
    const int c = c0 + (cy << 4) + j;
    out[((size_t)b * 256 + c) * LSEQ + t0 + tx] = acc[j];
  }
}

// ---------------------------------------------------------------------------
extern "C" void kernel_launch(void* const* d_in, const int* in_sizes, int n_in,
                              void* d_out, int out_size, void* d_ws, size_t ws_size,
                              hipStream_t stream) {
  const float* x     = (const float*)d_in[0];
  const float* W_in  = (const float*)d_in[1];
  const float* convw = (const float*)d_in[2];
  const float* convb = (const float*)d_in[3];
  const float* W_x   = (const float*)d_in[4];
  const float* W_dt  = (const float*)d_in[5];
  const float* b_dt  = (const float*)d_in[6];
  const float* A_log = (const float*)d_in[7];
  const float* Dvec  = (const float*)d_in[8];
  const float* W_out = (const float*)d_in[9];
  float* out = (float*)d_out;

  float* ws   = (float*)d_ws;
  float* xm   = ws + XM_OFF;
  float* gate = ws + GATE_OFF;
  float* xs   = ws + XS_OFF;
  float* dbl  = ws + DBL_OFF;
  float* ap   = ws + AP_OFF;   // aliases xm (dead after convx)
  float* ps   = ws + PS_OFF;   // aliases xm upper half

  // bf16-split buffers (dead after gemm_in)
  u16* xTh   = (u16*)(ws + SPLIT_OFF);   // [2][4096][256] bf16
  u16* xTl   = xTh + 2097152;
  u16* WinTh = xTl + 2097152;            // [1024][256] bf16
  u16* WinTl = WinTh + 262144;

  k_split<<<dim3(64, 4, 2), 256, 0, stream>>>(x, xTh, xTl, 256, 4096);
  k_split<<<dim3(16, 4, 1), 256, 0, stream>>>(W_in, WinTh, WinTl, 256, 1024);
  k_gemm_in_mfma<<<dim3(256, 8), 256, 0, stream>>>(xTh, xTl, WinTh, WinTl, xm, gate);
  k_convx<<<dim3(2048), 256, 0, stream>>>(xm, convw, convb, W_x, xs, dbl);
  k_scan1<<<dim3(NCH, 8, 2), 256, 0, stream>>>(xs, dbl, W_dt, b_dt, A_log, ap, ps);
  k_scan2<<<dim3(256), 256, 0, stream>>>(ap, ps);
  k_scan3<<<dim3(NCH, 8, 2), 256, 0, stream>>>(gate, xs, dbl, W_dt, b_dt, A_log, Dvec, ps);
  k_gemm_out<<<dim3(256, 2), 256, 0, stream>>>(xs, W_out, out);
}

// Round 11
// 403.801 us; speedup vs baseline: 1.5833x; 1.0062x over previous
//
#include <hip/hip_runtime.h>
#include <cstdint>
#include <cstddef>

// Sizes
#define LSEQ 4096
#define DI   512
#define NSTATE 16
#define TC 32     // scan chunk length
#define NCH 128   // number of chunks (LSEQ/TC)

// Workspace layout (floats), total 54,263,808 fl = 217 MB:
//  xm   : [8][4096][512] @ 0          (dead after convx -> reused by ap/ps)
//  gate : [8][4096][512] @ 16,777,216
//  xs   : [8][4096][512] @ 33,554,432 (becomes y in-place after scan3)
//  dbl  : [8][4096][48]  @ 50,331,648
//  split: bf16 bufs      @ 51,904,512 (dead after gemm_in)
//  ap   : [8][128][512][16] @ 0          (aliases xm)
//  ps   : [8][128][512][16] @ 8,388,608  (aliases xm upper half)
#define XM_OFF    0
#define GATE_OFF  16777216
#define XS_OFF    33554432
#define DBL_OFF   50331648
#define SPLIT_OFF 51904512
#define AP_OFF    0
#define PS_OFF    8388608

typedef unsigned short u16;
typedef __attribute__((ext_vector_type(8))) short s8v;    // 8 bf16 (4 VGPR)
typedef __attribute__((ext_vector_type(4))) float f4v;    // 4 fp32 acc
typedef __attribute__((ext_vector_type(4))) unsigned int u32x4;

#ifndef __has_builtin
#define __has_builtin(x) 0
#endif
#if __has_builtin(__builtin_amdgcn_global_load_lds)
#define USE_GLL 1
#else
#define USE_GLL 0
#endif

__device__ __forceinline__ float silu_f(float v) {
  return v * __frcp_rn(1.f + __expf(-v));
}
__device__ __forceinline__ float softplus_f(float v) {
  return fmaxf(v, 0.f) + __logf(1.f + __expf(-fabsf(v)));
}
__device__ __forceinline__ u16 bf16_hi(float v) {   // RNE truncate to bf16
  unsigned u = __float_as_uint(v);
  return (u16)((u + 0x7fffu + ((u >> 16) & 1u)) >> 16);
}
__device__ __forceinline__ float bf16_f(u16 h) { return __uint_as_float(((unsigned)h) << 16); }

__device__ __forceinline__ void gld16(const u16* g, u16* l, int lane) {
#if USE_GLL
  __builtin_amdgcn_global_load_lds((const __attribute__((address_space(1))) void*)g,
                                   (__attribute__((address_space(3))) void*)l, 16, 0, 0);
#else
  *(u32x4*)(l + lane * 8) = *(const u32x4*)g;
#endif
}

// powers r^1..r^16 via log-depth ladder (15 muls, depth ~4)
__device__ __forceinline__ void pow_ladder(float r, float* a) {
  const float r2 = r * r, r4 = r2 * r2, r8 = r4 * r4;
  a[0] = r;        a[1] = r2;       a[2] = r2 * r;   a[3] = r4;
  a[4] = r4 * r;   a[5] = r4 * r2;  a[6] = r4 * a[2]; a[7] = r8;
  a[8] = r8 * r;   a[9] = r8 * r2;  a[10] = r8 * a[2]; a[11] = r8 * r4;
  a[12] = r8 * a[4]; a[13] = r8 * a[5]; a[14] = r8 * a[6]; a[15] = r8 * r8;
}

// ---------------------------------------------------------------------------
// k_split: transpose fp32 [R][C] (batched) -> bf16 hi/lo [C][R]
// ---------------------------------------------------------------------------
__global__ __launch_bounds__(256) void k_split(const float* __restrict__ in,
                                               u16* __restrict__ oh,
                                               u16* __restrict__ ol,
                                               int R, int C) {
  __shared__ float tile[64][65];
  const size_t zoff = (size_t)blockIdx.z * R * C;
  in += zoff; oh += zoff; ol += zoff;
  const int c0 = blockIdx.x << 6, r0 = blockIdx.y << 6;
  const int tid = threadIdx.x;
  const int tx = tid & 63, ty = tid >> 6;
#pragma unroll
  for (int i = 0; i < 16; ++i) {
    const int r = ty + (i << 2);
    tile[r][tx] = in[(size_t)(r0 + r) * C + c0 + tx];
  }
  __syncthreads();
#pragma unroll
  for (int i = 0; i < 16; ++i) {
    const int cc = ty + (i << 2);
    const float v = tile[tx][cc];              // = in[r0+tx][c0+cc]
    const u16 h = bf16_hi(v);
    const size_t o = (size_t)(c0 + cc) * R + r0 + tx;
    oh[o] = h;
    ol[o] = bf16_hi(v - bf16_f(h));
  }
}

// ---------------------------------------------------------------------------
// Kernel 1: [xm|gate] = z @ W_in via bf16x2-split MFMA, 128x128 tile, BK=32.
// ---------------------------------------------------------------------------
__global__ __launch_bounds__(256) void k_gemm_in_mfma(const u16* __restrict__ xTh,
                                                      const u16* __restrict__ xTl,
                                                      const u16* __restrict__ Wh,
                                                      const u16* __restrict__ Wl,
                                                      float* __restrict__ xm,
                                                      float* __restrict__ gate) {
  __shared__ __attribute__((aligned(16))) u16 lds[4 * 128 * 32];  // Ah,Al,Bh,Bl
  u16* Ah = lds;
  u16* Al = lds + 4096;
  u16* Bh = lds + 8192;
  u16* Bl = lds + 12288;
  const int rt = blockIdx.x;            // 256 row tiles (128 rows each)
  const int nt = blockIdx.y;            // 8 col tiles (128 cols each)
  const int seq = rt >> 5, hl2 = rt & 31;
  const int b = seq & 1, dir = seq >> 1;
  const int tid = threadIdx.x;
  const int lane = tid & 63, wid = tid >> 6;
  const int wr = wid >> 1, wc = wid & 1;

  const u16* gsrc = (wid == 0) ? xTh : (wid == 1) ? xTl : (wid == 2) ? Wh : Wl;
  u16* ldst = lds + (wid << 12);
  size_t roff[8];
#pragma unroll
  for (int i = 0; i < 8; ++i) {
    const int r = (i << 4) + (lane >> 2);
    size_t off;
    if (wid < 2) {
      const int hl = (hl2 << 1) + (r >> 6), w = r & 63;
      const int hp = (dir & 2) ? 63 - hl : hl;
      const int wp = (dir & 1) ? 63 - w : w;
      off = ((size_t)((b << 12) + (hp << 6) + wp)) << 8;
    } else {
      off = ((size_t)((nt << 7) + r)) << 8;
    }
    roff[i] = off + ((lane & 3) << 3);
  }

  f4v acc[4][4];
  const f4v z4 = {0.f, 0.f, 0.f, 0.f};
#pragma unroll
  for (int m = 0; m < 4; ++m)
#pragma unroll
    for (int n = 0; n < 4; ++n) acc[m][n] = z4;

  const int fr = lane & 15;
  const int kg = (lane >> 4) << 3;

  for (int kc = 0; kc < 256; kc += 32) {
    __syncthreads();
#pragma unroll
    for (int i = 0; i < 8; ++i) gld16(gsrc + roff[i] + kc, ldst + (i << 9), lane);
    __syncthreads();
    s8v Afh[4], Afl[4], Bfh[4], Bfl[4];
#pragma unroll
    for (int m = 0; m < 4; ++m) {
      const int row = (wr << 6) + (m << 4) + fr;
      Afh[m] = *(const s8v*)&Ah[row * 32 + kg];
      Afl[m] = *(const s8v*)&Al[row * 32 + kg];
    }
#pragma unroll
    for (int n = 0; n < 4; ++n) {
      const int row = (wc << 6) + (n << 4) + fr;
      Bfh[n] = *(const s8v*)&Bh[row * 32 + kg];
      Bfl[n] = *(const s8v*)&Bl[row * 32 + kg];
    }
#pragma unroll
    for (int m = 0; m < 4; ++m)
#pragma unroll
      for (int n = 0; n < 4; ++n) {
        acc[m][n] = __builtin_amdgcn_mfma_f32_16x16x32_bf16(Afh[m], Bfh[n], acc[m][n], 0, 0, 0);
        acc[m][n] = __builtin_amdgcn_mfma_f32_16x16x32_bf16(Afh[m], Bfl[n], acc[m][n], 0, 0, 0);
        acc[m][n] = __builtin_amdgcn_mfma_f32_16x16x32_bf16(Afl[m], Bfh[n], acc[m][n], 0, 0, 0);
      }
  }
  const int rg = (lane >> 4) << 2;
  float* obuf = (nt & 4) ? gate : xm;
  const int ncol = (nt & 3) << 7;
  float* obase = obuf + ((size_t)((rt << 7) + (wr << 6) + rg)) * DI + ncol + (wc << 6) + fr;
#pragma unroll
  for (int m = 0; m < 4; ++m)
#pragma unroll
    for (int n = 0; n < 4; ++n)
#pragma unroll
      for (int j = 0; j < 4; ++j)
        obase[(size_t)((m << 4) + j) * DI + (n << 4)] = acc[m][n][j];
}

// ---------------------------------------------------------------------------
// Kernel 2+3 fused (k_convx) v2: each thread owns 2 adjacent d columns
// (float2), preloads all 19 rows into registers (19 outstanding loads) to
// break the rolling-window dependence, then conv+silu -> xs + LDS, then
// dbl = xs @ W_x.
// ---------------------------------------------------------------------------
__global__ __launch_bounds__(256) void k_convx(const float* __restrict__ xmb,
                                               const float* __restrict__ cw,
                                               const float* __restrict__ cb,
                                               const float* __restrict__ Wx,
                                               float* __restrict__ xs,
                                               float* __restrict__ dbl) {
  __shared__ float xsh[16][512];
  const int rb  = blockIdx.x;
  const int tid = threadIdx.x;
  const int r0g = rb << 4;            // global row (seq*4096 + t)
  const int t0  = r0g & 4095;         // within-seq t (0 only at seq start)
  const int d2  = tid << 1;           // 2 adjacent d columns per thread
  const float4 wA = *(const float4*)&cw[d2 * 4];
  const float4 wB = *(const float4*)&cw[d2 * 4 + 4];
  const float bx = cb[d2], by = cb[d2 + 1];

  float2 xv[19];
#pragma unroll
  for (int i = 0; i < 16; ++i)
    xv[i + 3] = *(const float2*)&xmb[(size_t)(r0g + i) * DI + d2];
  if (t0 != 0) {
    xv[0] = *(const float2*)&xmb[((size_t)r0g - 3) * DI + d2];
    xv[1] = *(const float2*)&xmb[((size_t)r0g - 2) * DI + d2];
    xv[2] = *(const float2*)&xmb[((size_t)r0g - 1) * DI + d2];
  } else {
    xv[0] = make_float2(0.f, 0.f);
    xv[1] = make_float2(0.f, 0.f);
    xv[2] = make_float2(0.f, 0.f);
  }
  float* xsg = xs + (size_t)r0g * DI + d2;
#pragma unroll
  for (int i = 0; i < 16; ++i) {
    const float vx = fmaf(wA.x, xv[i].x, fmaf(wA.y, xv[i + 1].x,
                     fmaf(wA.z, xv[i + 2].x, fmaf(wA.w, xv[i + 3].x, bx))));
    const float vy = fmaf(wB.x, xv[i].y, fmaf(wB.y, xv[i + 1].y,
                     fmaf(wB.z, xv[i + 2].y, fmaf(wB.w, xv[i + 3].y, by))));
    float2 sv;
    sv.x = silu_f(vx);
    sv.y = silu_f(vy);
    *(float2*)&xsh[i][d2] = sv;
    *(float2*)&xsg[(size_t)i * DI] = sv;
  }
  __syncthreads();
  if (tid < 192) {
    const int col = tid % 48;
    const int rg  = tid / 48;
    float a0 = 0.f, a1 = 0.f, a2 = 0.f, a3 = 0.f;
    for (int k = 0; k < 512; k += 4) {
      float wv0 = Wx[(size_t)(k + 0) * 48 + col];
      float wv1 = Wx[(size_t)(k + 1) * 48 + col];
      float wv2 = Wx[(size_t)(k + 2) * 48 + col];
      float wv3 = Wx[(size_t)(k + 3) * 48 + col];
      const float4 x0 = *(const float4*)&xsh[rg * 4 + 0][k];
      const float4 x1 = *(const float4*)&xsh[rg * 4 + 1][k];
      const float4 x2 = *(const float4*)&xsh[rg * 4 + 2][k];
      const float4 x3 = *(const float4*)&xsh[rg * 4 + 3][k];
      a0 = fmaf(x0.x, wv0, fmaf(x0.y, wv1, fmaf(x0.z, wv2, fmaf(x0.w, wv3, a0))));
      a1 = fmaf(x1.x, wv0, fmaf(x1.y, wv1, fmaf(x1.z, wv2, fmaf(x1.w, wv3, a1))));
      a2 = fmaf(x2.x, wv0, fmaf(x2.y, wv1, fmaf(x2.z, wv2, fmaf(x2.w, wv3, a2))));
      a3 = fmaf(x3.x, wv0, fmaf(x3.y, wv1, fmaf(x3.z, wv2, fmaf(x3.w, wv3, a3))));
    }
    const size_t base = ((size_t)rb * 16 + rg * 4) * 48 + col;
    dbl[base] = a0; dbl[base + 48] = a1; dbl[base + 96] = a2; dbl[base + 144] = a3;
  }
}

// ---------------------------------------------------------------------------
// Kernel 4 (scan pass 1): r = sigmoid(-dtp) == exp(-softplus(dtp));
// dtv = -log(r). One rcp+2 trans per t in fast path.
// ---------------------------------------------------------------------------
__global__ __launch_bounds__(256) void k_scan1(const float* __restrict__ xs,
                                               const float* __restrict__ dbl,
                                               const float* __restrict__ Wdt,
                                               const float* __restrict__ bdt,
                                               const float* __restrict__ Alog,
                                               float* __restrict__ aprod,
                                               float* __restrict__ pstate) {
  __shared__ float dsh[TC * 48];
  const int ch = blockIdx.x, seq = blockIdx.y;
  const int tid = threadIdx.x;
  const int d = (blockIdx.z << 8) + tid;
  const int t0 = ch * TC;
  const float* dsrc = dbl + ((size_t)seq * LSEQ + t0) * 48;
#pragma unroll
  for (int i = 0; i < 6; ++i) dsh[tid + (i << 8)] = dsrc[tid + (i << 8)];
  float wdt[16], Aa[16], st[16], P[16];
#pragma unroll
  for (int k = 0; k < 16; ++k) wdt[k] = Wdt[(size_t)k * DI + d];
  const float bd = bdt[d];
  bool fast = true;
#pragma unroll
  for (int s = 0; s < NSTATE; ++s) {
    const float Av = __expf(Alog[d * NSTATE + s]);
    Aa[s] = -Av;
    fast = fast && (fabsf(Av - (float)(s + 1)) < 1e-3f);
    st[s] = 0.f; P[s] = 1.f;
  }
  const float* xsrc = xs + ((size_t)seq * LSEQ + t0) * DI + d;
  __syncthreads();
  if (fast) {
    float Rp = 1.f;
    for (int t = 0; t < TC; ++t) {
      const float* dr = &dsh[t * 48];
      float dtp = bd;
#pragma unroll
      for (int k = 0; k < 16; ++k) dtp = fmaf(dr[k], wdt[k], dtp);
      const float r = __frcp_rn(1.f + __expf(fminf(dtp, 80.f)));
      const float dtv = -__logf(r);
      const float u = dtv * xsrc[(size_t)t * DI];
      float a[16];
      pow_ladder(r, a);
      Rp *= r;
#pragma unroll
      for (int s = 0; s < NSTATE; ++s) st[s] = fmaf(a[s], st[s], u * dr[16 + s]);
    }
    pow_ladder(Rp, P);
  } else {
    for (int t = 0; t < TC; ++t) {
      const float* dr = &dsh[t * 48];
      float dtp = bd;
#pragma unroll
      for (int k = 0; k < 16; ++k) dtp = fmaf(dr[k], wdt[k], dtp);
      const float dtv = softplus_f(dtp);
      const float u = dtv * xsrc[(size_t)t * DI];
#pragma unroll
      for (int s = 0; s < NSTATE; ++s) {
        const float a = __expf(dtv * Aa[s]);
        st[s] = fmaf(a, st[s], u * dr[16 + s]);
        P[s] *= a;
      }
    }
  }
  float* ap = aprod  + (((size_t)seq * NCH + ch) * DI + d) * NSTATE;
  float* pp = pstate + (((size_t)seq * NCH + ch) * DI + d) * NSTATE;
#pragma unroll
  for (int s = 0; s < NSTATE; s += 4) {
    *(float4*)&ap[s] = make_float4(P[s], P[s + 1], P[s + 2], P[s + 3]);
    *(float4*)&pp[s] = make_float4(st[s], st[s + 1], st[s + 2], st[s + 3]);
  }
}

// ---------------------------------------------------------------------------
// Kernel 5 (scan pass 2): cross-chunk scan; pstate becomes hinit in-place.
// ---------------------------------------------------------------------------
__global__ __launch_bounds__(256) void k_scan2(const float* __restrict__ aprod,
                                               float* __restrict__ pstate) {
  const int flat = blockIdx.x * 256 + threadIdx.x;
  const int seq = flat >> 13;
  const int rem = flat & 8191;
  const size_t stride = (size_t)DI * NSTATE;
  const size_t base = (size_t)seq * NCH * stride + rem;
  float h = 0.f;
  for (int ch = 0; ch < NCH; ++ch) {
    const size_t o = base + (size_t)ch * stride;
    const float a = aprod[o];
    const float bsum = pstate[o];
    pstate[o] = h;
    h = fmaf(a, h, bsum);
  }
}

// ---------------------------------------------------------------------------
// Kernel 6 (scan pass 3): same sigmoid fast path; y over xs in place.
// ---------------------------------------------------------------------------
__global__ __launch_bounds__(256) void k_scan3(const float* __restrict__ gate,
                                               float* __restrict__ xs,
                                               const float* __restrict__ dbl,
                                               const float* __restrict__ Wdt,
                                               const float* __restrict__ bdt,
                                               const float* __restrict__ Alog,
                                               const float* __restrict__ Dv,
                                               const float* __restrict__ hinit) {
  __shared__ float dsh[TC * 48];
  const int ch = blockIdx.x, seq = blockIdx.y;
  const int tid = threadIdx.x;
  const int d = (blockIdx.z << 8) + tid;
  const int t0 = ch * TC;
  const float* dsrc = dbl + ((size_t)seq * LSEQ + t0) * 48;
#pragma unroll
  for (int i = 0; i < 6; ++i) dsh[tid + (i << 8)] = dsrc[tid + (i << 8)];
  float wdt[16], Aa[16], st[16];
#pragma unroll
  for (int k = 0; k < 16; ++k) wdt[k] = Wdt[(size_t)k * DI + d];
  const float bd = bdt[d];
  const float Dp = Dv[d];
  const float* hp = hinit + (((size_t)seq * NCH + ch) * DI + d) * NSTATE;
  bool fast = true;
#pragma unroll
  for (int s = 0; s < NSTATE; ++s) {
    const float Av = __expf(Alog[d * NSTATE + s]);
    Aa[s] = -Av;
    fast = fast && (fabsf(Av - (float)(s + 1)) < 1e-3f);
    st[s] = hp[s];
  }
  float* xrow = xs + ((size_t)seq * LSEQ + t0) * DI + d;
  const float* grow = gate + ((size_t)seq * LSEQ + t0) * DI + d;
  __syncthreads();
  if (fast) {
    for (int t = 0; t < TC; ++t) {
      const float* dr = &dsh[t * 48];
      float dtp = bd;
#pragma unroll
      for (int k = 0; k < 16; ++k) dtp = fmaf(dr[k], wdt[k], dtp);
      const float r = __frcp_rn(1.f + __expf(fminf(dtp, 80.f)));
      const float dtv = -__logf(r);
      const float xsv = xrow[(size_t)t * DI];
      const float u = dtv * xsv;
      float a[16];
      pow_ladder(r, a);
      float y = 0.f;
#pragma unroll
      for (int s = 0; s < NSTATE; ++s) {
        st[s] = fmaf(a[s], st[s], u * dr[16 + s]);
        y = fmaf(st[s], dr[32 + s], y);
      }
      y = fmaf(xsv, Dp, y);
      y *= silu_f(grow[(size_t)t * DI]);
      xrow[(size_t)t * DI] = y;
    }
  } else {
    for (int t = 0; t < TC; ++t) {
      const float* dr = &dsh[t * 48];
      float dtp = bd;
#pragma unroll
      for (int k = 0; k < 16; ++k) dtp = fmaf(dr[k], wdt[k], dtp);
      const float dtv = softplus_f(dtp);
      const float xsv = xrow[(size_t)t * DI];
      const float u = dtv * xsv;
      float y = 0.f;
#pragma unroll
      for (int s = 0; s < NSTATE; ++s) {
        const float a = __expf(dtv * Aa[s]);
        st[s] = fmaf(a, st[s], u * dr[16 + s]);
        y = fmaf(st[s], dr[32 + s], y);
      }
      y = fmaf(xsv, Dp, y);
      y *= silu_f(grow[(size_t)t * DI]);
      xrow[(size_t)t * DI] = y;
    }
  }
}

// ---------------------------------------------------------------------------
// Kernel 8 (fused combine + out-proj), v2: 32 t-rows x 128 c-cols per block.
// ---------------------------------------------------------------------------
__global__ __launch_bounds__(256, 2) void k_gemm_out(const float* __restrict__ y,
                                                     const float* __restrict__ Wout,
                                                     float* __restrict__ out) {
  __shared__ float Ash[64 * 33];
  __shared__ float Bsh[64 * 132];
  const int bx = blockIdx.x;                 // 0..255 : b*128 + tt
  const int b = bx >> 7, tt = bx & 127;
  const int t0 = tt << 5;                    // 32 rows
  const int c0 = blockIdx.y << 7;            // 128 cols
  const int tid = threadIdx.x;
  const int h = t0 >> 6, hf = 63 - h;        // constant per block
  const int w0 = t0 & 63;
  const int ar = tid >> 3, ak = tid & 7;
  const int w = w0 + ar, wf = 63 - w;
  const size_t row0 = ((size_t)(0 + b) * LSEQ + (h << 6) + w) * DI;
  const size_t row1 = ((size_t)(2 + b) * LSEQ + (h << 6) + wf) * DI;
  const size_t row2 = ((size_t)(4 + b) * LSEQ + (hf << 6) + w) * DI;
  const size_t row3 = ((size_t)(6 + b) * LSEQ + (hf << 6) + wf) * DI;
  const int bk = tid >> 3, bc = tid & 7;
  const int tx = tid & 31, cy = tid >> 5;    // 8 c-groups of 16 cols
  float acc[16];
#pragma unroll
  for (int j = 0; j < 16; ++j) acc[j] = 0.f;

  for (int kc = 0; kc < 512; kc += 64) {
#pragma unroll
    for (int f = 0; f < 2; ++f) {
      const int kl = (ak << 3) + (f << 2);
      const int k = kl + kc;
      const float4 v0 = *(const float4*)&y[row0 + k];
      const float4 v1 = *(const float4*)&y[row1 + k];
      const float4 v2 = *(const float4*)&y[row2 + k];
      const float4 v3 = *(const float4*)&y[row3 + k];
      Ash[(kl + 0) * 33 + ar] = 0.25f * (v0.x + v1.x + v2.x + v3.x);
      Ash[(kl + 1) * 33 + ar] = 0.25f * (v0.y + v1.y + v2.y + v3.y);
      Ash[(kl + 2) * 33 + ar] = 0.25f * (v0.z + v1.z + v2.z + v3.z);
      Ash[(kl + 3) * 33 + ar] = 0.25f * (v0.w + v1.w + v2.w + v3.w);
    }
#pragma unroll
    for (int rr = 0; rr < 2; ++rr) {
      const int kk = bk + (rr << 5);
#pragma unroll
      for (int i = 0; i < 4; ++i) {
        const int c = (bc << 2) + (i << 5);
        *(float4*)&Bsh[kk * 132 + c] =
            *(const float4*)&Wout[(size_t)(kc + kk) * 256 + c0 + c];
      }
    }
    __syncthreads();
#pragma unroll
    for (int kk = 0; kk < 64; ++kk) {
      const float a = Ash[kk * 33 + tx];
      const float* bp = &Bsh[kk * 132 + (cy << 4)];
      const float4 b0 = *(const float4*)&bp[0];
      const float4 b1 = *(const float4*)&bp[4];
      const float4 b2 = *(const float4*)&bp[8];
      const float4 b3 = *(const float4*)&bp[12];
      acc[0]  = fmaf(a, b0.x, acc[0]);   acc[1]  = fmaf(a, b0.y, acc[1]);
      acc[2]  = fmaf(a, b0.z, acc[2]);   acc[3]  = fmaf(a, b0.w, acc[3]);
      acc[4]  = fmaf(a, b1.x, acc[4]);   acc[5]  = fmaf(a, b1.y, acc[5]);
      acc[6]  = fmaf(a, b1.z, acc[6]);   acc[7]  = fmaf(a, b1.w, acc[7]);
      acc[8]  = fmaf(a, b2.x, acc[8]);   acc[9]  = fmaf(a, b2.y, acc[9]);
      acc[10] = fmaf(a, b2.z, acc[10]);  acc[11] = fmaf(a, b2.w, acc[11]);
      acc[12] = fmaf(a, b3.x, acc[12]);  acc[13] = fmaf(a, b3.y, acc[13]);
      acc[14] = fmaf(a, b3.z, acc[14]);  acc[15] = fmaf(a, b3.w, acc[15]);
    }
    __syncthreads();
  }
#pragma unroll
  for (int j = 0; j < 16; ++j) {
    const int c = c0 + (cy << 4) + j;
    out[((size_t)b * 256 + c) * LSEQ + t0 + tx] = acc[j];
  }
}

// ---------------------------------------------------------------------------
extern "C" void kernel_launch(void* const* d_in, const int* in_sizes, int n_in,
                              void* d_out, int out_size, void* d_ws, size_t ws_size,
                              hipStream_t stream) {
  const float* x     = (const float*)d_in[0];
  const float* W_in  = (const float*)d_in[1];
  const float* convw = (const float*)d_in[2];
  const float* convb = (const float*)d_in[3];
  const float* W_x   = (const float*)d_in[4];
  const float* W_dt  = (const float*)d_in[5];
  const float* b_dt  = (const float*)d_in[6];
  const float* A_log = (const float*)d_in[7];
  const float* Dvec  = (const float*)d_in[8];
  const float* W_out = (const float*)d_in[9];
  float* out = (float*)d_out;

  float* ws   = (float*)d_ws;
  float* xm   = ws + XM_OFF;
  float* gate = ws + GATE_OFF;
  float* xs   = ws + XS_OFF;
  float* dbl  = ws + DBL_OFF;
  float* ap   = ws + AP_OFF;   // aliases xm (dead after convx)
  float* ps   = ws + PS_OFF;   // aliases xm upper half

  // bf16-split buffers (dead after gemm_in)
  u16* xTh   = (u16*)(ws + SPLIT_OFF);   // [2][4096][256] bf16
  u16* xTl   = xTh + 2097152;
  u16* WinTh = xTl + 2097152;            // [1024][256] bf16
  u16* WinTl = WinTh + 262144;

  k_split<<<dim3(64, 4, 2), 256, 0, stream>>>(x, xTh, xTl, 256, 4096);
  k_split<<<dim3(16, 4, 1), 256, 0, stream>>>(W_in, WinTh, WinTl, 256, 1024);
  k_gemm_in_mfma<<<dim3(256, 8), 256, 0, stream>>>(xTh, xTl, WinTh, WinTl, xm, gate);
  k_convx<<<dim3(2048), 256, 0, stream>>>(xm, convw, convb, W_x, xs, dbl);
  k_scan1<<<dim3(NCH, 8, 2), 256, 0, stream>>>(xs, dbl, W_dt, b_dt, A_log, ap, ps);
  k_scan2<<<dim3(256), 256, 0, stream>>>(ap, ps);
  k_scan3<<<dim3(NCH, 8, 2), 256, 0, stream>>>(gate, xs, dbl, W_dt, b_dt, A_log, Dvec, ps);
  k_gemm_out<<<dim3(256, 2), 256, 0, stream>>>(xs, W_out, out);
}